// Round 17
// baseline (85.889 us; speedup 1.0000x reference)
//
#include <hip/hip_runtime.h>

// B=512, N=64, H=256, LAT=128, HEADS=4, HC=64, NF=64, L=3, R=8, SCAL=2.0, NB=4, Din=384

typedef float float4v __attribute__((ext_vector_type(4)));
typedef short short8v __attribute__((ext_vector_type(8)));
typedef uint  uint4v  __attribute__((ext_vector_type(4)));

struct alignas(8) us4 { ushort x, y, z, w; };

// f32 ws offsets (floats)
#define ZA_OFF 0UL          // zA[512][8]
#define HZ_OFF 4096UL       // hz[3][512][256] f32
#define EZ_OFF 397312UL     // ez[3][2][512][4] f32
// ushort ws offsets (ushorts); f32 region ends at float 409600 -> ushort 819200
#define XBF_U   819200UL    // x bf16 [512][64][256]
#define ZBF_U   9207808UL   // z bf16 [512][128]
#define GWBF_U  9273344UL   // gatW bf16 [3][256][384]
#define WZST_U  9568256UL   // z2n_w bf16 staging-ordered [64 bn][4 kk][4 wv][4 frag][64 ln][8]
#define PW_U    11665408UL  // pred weights bf16 [80][256]
#define WST_U   11759616UL  // wstage bf16 [3][8][4 head][5 frag][64 lane][8]

__device__ inline ushort f2bf(float f) {
    uint u = __float_as_uint(f);
    uint r = (u + 0x7FFFu + ((u >> 16) & 1u)) >> 16;
    return (ushort)r;
}
__device__ inline float bf2f(ushort u) { return __uint_as_float(((uint)u) << 16); }

__device__ inline uint cvtpk(float a, float b) {
    uint r;
    asm("v_cvt_pk_bf16_f32 %0, %1, %2" : "=v"(r) : "v"(a), "v"(b));
    return r;
}

// swizzled x-mode LDS index (ushort units): row r (0..63), ushort col cu (0..255)
__device__ inline int xidx(int r, int cu) {
    int ch = cu >> 3;
    return r * 256 + (((ch ^ (r & 7))) << 3) + (cu & 7);
}

struct P3 { short8v b0, b1, b2; };
__device__ inline P3 loadP3(const ushort* pw, int lo, int hi, int kk) {
    P3 f;
    f.b0 = *(const short8v*)(pw + (size_t)(      lo)*256 + kk*32 + hi*8);
    f.b1 = *(const short8v*)(pw + (size_t)(16  + lo)*256 + kk*32 + hi*8);
    f.b2 = *(const short8v*)(pw + (size_t)(32  + lo)*256 + kk*32 + hi*8);
    return f;
}
struct P2 { short8v b3, b4; };
__device__ inline P2 loadP2(const ushort* pw, int lo, int hi, int kk) {
    P2 f;
    f.b3 = *(const short8v*)(pw + (size_t)(48 + lo)*256 + kk*32 + hi*8);
    f.b4 = *(const short8v*)(pw + (size_t)(64 + lo)*256 + kk*32 + hi*8);
    return f;
}

__device__ inline void gll(const ushort* src, ushort* dst) {
    __builtin_amdgcn_global_load_lds(
        (const __attribute__((address_space(1))) void*)src,
        (__attribute__((address_space(3))) void*)dst, 16, 0, 0);
}

// wave-private slice staging: owner (c0h=0) frags {0,1,4}, other frags {2,3}
__device__ inline void stageW(ushort* dstHead, const ushort* srcHead, int c0h, int ln) {
    if (c0h == 0) {
        gll(srcHead +        ln*8, dstHead);
        gll(srcHead +  512 + ln*8, dstHead + 512);
        gll(srcHead + 2048 + ln*8, dstHead + 2048);
    } else {
        gll(srcHead + 1024 + ln*8, dstHead + 1024);
        gll(srcHead + 1536 + ln*8, dstHead + 1536);
    }
}

// z2n: wave stages its own 2048-us quarter of one slice (4 chunks of 512 us)
__device__ inline void stageZ(ushort* dst, const ushort* src, int ln) {
    #pragma unroll
    for (int c = 0; c < 4; ++c)
        gll(src + c*512 + ln*8, dst + c*512);
}

// ---------------------------------------------------------------- setup ----
__global__ __launch_bounds__(256) void k_setup(
    const float* __restrict__ z, const float* __restrict__ z2nA,
    const float* __restrict__ nodeW, const float* __restrict__ nodeA, const float* __restrict__ nodeB,
    const float* __restrict__ adjW, const float* __restrict__ adjA, const float* __restrict__ adjB,
    const float* __restrict__ bondW, const float* __restrict__ bondA, const float* __restrict__ bondB,
    const float* __restrict__ gatW, const float* __restrict__ z2nw,
    const float* __restrict__ asrcp, const float* __restrict__ adstp,
    float* __restrict__ wsf)
{
    ushort* wsu = (ushort*)wsf;
    int gid = blockIdx.x * 256 + threadIdx.x;
    if (gid < 4096) {                       // zA[b][r] = z[b]·A[r]
        int b = gid >> 3, r = gid & 7;
        const float* zp = z + (size_t)b * 128;
        const float* ap = z2nA + (size_t)r * 128;
        float s = 0.f;
        #pragma unroll 8
        for (int k = 0; k < 128; ++k) s += zp[k] * ap[k];
        wsf[ZA_OFF + gid] = s;
    } else if (gid < 24576) {               // pw[80][256] bf16, LoRA folded
        int idx = gid - 4096;
        int r = idx >> 8, c = idx & 255;
        float v = 0.f;
        if (r < 64) {
            float s = 0.f;
            #pragma unroll
            for (int k = 0; k < 8; ++k) s += nodeB[r*8+k] * nodeA[k*256+c];
            v = nodeW[r*256+c] + 2.0f * s;
        } else if (r < 66) {
            int off = (r - 64) * 256 + c;
            float s = 0.f;
            #pragma unroll
            for (int k = 0; k < 8; ++k) s += adjB[k] * adjA[k*512+off];
            v = adjW[off] + 2.0f * s;
        } else if (r < 70) {
            int q = r - 66;
            float s = 0.f;
            #pragma unroll
            for (int k = 0; k < 8; ++k) s += bondB[q*8+k] * bondA[k*512+c];
            v = bondW[q*512+c] + 2.0f * s;
        } else if (r < 74) {
            int q = r - 70;
            float s = 0.f;
            #pragma unroll
            for (int k = 0; k < 8; ++k) s += bondB[q*8+k] * bondA[k*512+256+c];
            v = bondW[q*512+256+c] + 2.0f * s;
        }
        wsu[PW_U + idx] = f2bf(v);
    } else if (gid < 55296) {               // wstage element (16B = 8 bf16)
        int idx = gid - 24576;               // [0, 30720)
        int lkk = idx / 1280;
        int rem = idx - lkk * 1280;
        int head = rem / 320;
        int rem2 = rem - head * 320;
        int frag = rem2 >> 6;
        int ln = rem2 & 63;
        int lo = ln & 15, hi = ln >> 4;
        int l = lkk >> 3, kk = lkk & 7;
        ushort* dst = wsu + WST_U + (size_t)idx * 8;
        if (frag < 4) {
            const float* srcw = gatW + ((size_t)(l*256 + head*64 + frag*16 + lo))*384 + kk*32 + hi*8;
            #pragma unroll
            for (int j = 0; j < 8; ++j) dst[j] = f2bf(srcw[j]);
        } else {
            float s[8] = {0.f,0.f,0.f,0.f,0.f,0.f,0.f,0.f};
            if (lo < 2) {
                const float* av = (lo == 0 ? asrcp : adstp) + l*256 + head*64;
                const float* wp = gatW + ((size_t)(l*256 + head*64))*384 + kk*32 + hi*8;
                for (int hc = 0; hc < 64; ++hc) {
                    float a = av[hc];
                    const float* wr = wp + (size_t)hc * 384;
                    #pragma unroll
                    for (int j = 0; j < 8; ++j) s[j] += wr[j] * a;
                }
            }
            #pragma unroll
            for (int j = 0; j < 8; ++j) dst[j] = f2bf(s[j]);
        }
    } else {                                // conversions
        int cid = gid - 55296;
        if (cid < 16384) {                  // z -> bf16
            float4 v = ((const float4*)z)[cid];
            us4 o; o.x = f2bf(v.x); o.y = f2bf(v.y); o.z = f2bf(v.z); o.w = f2bf(v.w);
            ((us4*)(wsu + ZBF_U))[cid] = o;
        } else if (cid < 90112) {           // gatW -> bf16
            int idx = cid - 16384;
            float4 v = ((const float4*)gatW)[idx];
            us4 o; o.x = f2bf(v.x); o.y = f2bf(v.y); o.z = f2bf(v.z); o.w = f2bf(v.w);
            ((us4*)(wsu + GWBF_U))[idx] = o;
        } else if (cid < 352256) {
            // z2n_w -> WZST, ONE 16B chunk per thread (coalesced writes)
            int c = cid - 90112;            // chunk index [0, 262144)
            int ln = c & 63, frag = (c >> 6) & 3, wv = (c >> 8) & 3,
                kk = (c >> 10) & 3, bn = c >> 12;
            int lo2 = ln & 15, hi2 = ln >> 4;
            const float* src = z2nw + (size_t)(bn*256 + wv*64 + frag*16 + lo2)*128
                                    + kk*32 + hi2*8;
            float4 v0 = *(const float4*)src;
            float4 v1 = *(const float4*)(src + 4);
            ushort* dst = wsu + WZST_U + (size_t)c * 8;
            us4 o0, o1;
            o0.x = f2bf(v0.x); o0.y = f2bf(v0.y); o0.z = f2bf(v0.z); o0.w = f2bf(v0.w);
            o1.x = f2bf(v1.x); o1.y = f2bf(v1.y); o1.z = f2bf(v1.z); o1.w = f2bf(v1.w);
            *(us4*)dst = o0;
            *(us4*)(dst + 4) = o1;
        }
    }
}

// ---------------------------------------- z_to_nodes + hz (merged grid) ----
__global__ __launch_bounds__(256) void k_z2n(
    const float* __restrict__ bias, const float* __restrict__ lB,
    const float* __restrict__ asrcp, const float* __restrict__ adstp,
    float* __restrict__ wsf)
{
    __shared__ ushort wbuf[16384];          // 2 x 8192 us (32 KB) W double-buffer
    ushort* wsu = (ushort*)wsf;
    int t = threadIdx.x;
    int w = t >> 6, ln = t & 63, lo = ln & 15, hi = ln >> 4;

    if (blockIdx.x >= 512) {
        // ---- hz part (24 blocks): hz[l][b][o2] = z[b]·Wz[l][o2]; ez dots
        int bid2 = blockIdx.x - 512;
        int l = bid2 >> 3, bg = bid2 & 7;
        const ushort* wz = wsu + GWBF_U + (size_t)l * 98304;   // [256][384]
        const ushort* zb = wsu + ZBF_U + (size_t)bg * 64 * 128;
        float4v acc[4][4];
        #pragma unroll
        for (int m = 0; m < 4; ++m)
            #pragma unroll
            for (int n = 0; n < 4; ++n) acc[m][n] = (float4v)(0.f);
        #pragma unroll
        for (int kk = 0; kk < 4; ++kk) {
            short8v a[4], bq[4];
            #pragma unroll
            for (int m = 0; m < 4; ++m)
                a[m] = *(const short8v*)(wz + (size_t)(w*64 + m*16 + lo)*384 + 256 + kk*32 + hi*8);
            #pragma unroll
            for (int n = 0; n < 4; ++n)
                bq[n] = *(const short8v*)(zb + (size_t)(n*16 + lo)*128 + kk*32 + hi*8);
            #pragma unroll
            for (int m = 0; m < 4; ++m)
                #pragma unroll
                for (int n = 0; n < 4; ++n)
                    acc[m][n] = __builtin_amdgcn_mfma_f32_16x16x32_bf16(a[m], bq[n], acc[m][n], 0, 0, 0);
        }
        float* hzp = wsf + HZ_OFF + (size_t)l * 131072;
        #pragma unroll
        for (int m = 0; m < 4; ++m)
            #pragma unroll
            for (int n = 0; n < 4; ++n)
                #pragma unroll
                for (int q = 0; q < 4; ++q)
                    hzp[(size_t)(bg*64 + n*16 + lo)*256 + w*64 + m*16 + hi*4 + q] = acc[m][n][q];
        float as_[4][4], ad_[4][4];
        #pragma unroll
        for (int m = 0; m < 4; ++m)
            #pragma unroll
            for (int q = 0; q < 4; ++q) {
                as_[m][q] = asrcp[l*256 + w*64 + m*16 + hi*4 + q];
                ad_[m][q] = adstp[l*256 + w*64 + m*16 + hi*4 + q];
            }
        #pragma unroll
        for (int n = 0; n < 4; ++n) {
            float ss = 0.f, dd = 0.f;
            #pragma unroll
            for (int m = 0; m < 4; ++m)
                #pragma unroll
                for (int q = 0; q < 4; ++q) {
                    ss += acc[m][n][q] * as_[m][q];
                    dd += acc[m][n][q] * ad_[m][q];
                }
            ss += __shfl_xor(ss, 16); ss += __shfl_xor(ss, 32);
            dd += __shfl_xor(dd, 16); dd += __shfl_xor(dd, 32);
            if (hi == 0) {
                int b = bg*64 + n*16 + lo;
                wsf[EZ_OFF + (size_t)(l*2 + 0)*2048 + (size_t)b*4 + w] = ss;
                wsf[EZ_OFF + (size_t)(l*2 + 1)*2048 + (size_t)b*4 + w] = dd;
            }
        }
        return;
    }

    // ---- z2n part (512 blocks): W via LDS-staged double buffer
    int bm = blockIdx.x >> 6, bn = blockIdx.x & 63;
    int brow0 = bm * 64;
    int o0 = bn * 256 + w * 64;
    const ushort* wst = wsu + WZST_U + (size_t)bn * 32768;   // 4 slices x 8192 us
    const ushort* zb = wsu + ZBF_U;
    float4v acc[4][4];
    #pragma unroll
    for (int m = 0; m < 4; ++m)
        #pragma unroll
        for (int n = 0; n < 4; ++n) acc[m][n] = (float4v)(0.f);

    // prologue: stage slice 0 (each wave its own quarter)
    stageZ(wbuf + w*2048, wst + w*2048, ln);

    #pragma unroll
    for (int kk = 0; kk < 4; ++kk) {
        __syncthreads();   // slice kk landed (barrier drains vmcnt) + prev reads retired
        if (kk < 3)
            stageZ(wbuf + ((kk+1)&1)*8192 + w*2048,
                   wst + (size_t)(kk+1)*8192 + w*2048, ln);
        short8v a[4], bq[4];
        #pragma unroll
        for (int m = 0; m < 4; ++m)
            a[m] = *(const short8v*)&wbuf[(kk&1)*8192 + w*2048 + m*512 + ln*8];
        #pragma unroll
        for (int n = 0; n < 4; ++n)
            bq[n] = *(const short8v*)(zb + (size_t)(brow0 + n*16 + lo)*128 + kk*32 + hi*8);
        #pragma unroll
        for (int m = 0; m < 4; ++m)
            #pragma unroll
            for (int n = 0; n < 4; ++n)
                acc[m][n] = __builtin_amdgcn_mfma_f32_16x16x32_bf16(a[m], bq[n], acc[m][n], 0, 0, 0);
    }
    const float* zA = wsf + ZA_OFF;
    float4 za0[4], za1[4];
    #pragma unroll
    for (int n = 0; n < 4; ++n) {
        int brow = brow0 + n*16 + lo;
        za0[n] = *(const float4*)&zA[brow*8];
        za1[n] = *(const float4*)&zA[brow*8 + 4];
    }
    #pragma unroll
    for (int m = 0; m < 4; ++m) {
        float lor[4][4]; float bs[4];
        #pragma unroll
        for (int q = 0; q < 4; ++q) {
            int o = o0 + m*16 + hi*4 + q;
            float4 b20 = *(const float4*)&lB[(size_t)o*8];
            float4 b21 = *(const float4*)&lB[(size_t)o*8 + 4];
            bs[q] = bias[o];
            #pragma unroll
            for (int n = 0; n < 4; ++n)
                lor[n][q] = za0[n].x*b20.x + za0[n].y*b20.y + za0[n].z*b20.z + za0[n].w*b20.w
                          + za1[n].x*b21.x + za1[n].y*b21.y + za1[n].z*b21.z + za1[n].w*b21.w;
        }
        #pragma unroll
        for (int n = 0; n < 4; ++n) {
            int brow = brow0 + n*16 + lo;
            float v0 = acc[m][n][0] + 2.f*lor[n][0] + bs[0]; v0 = v0 > 0.f ? v0 : 0.f;
            float v1 = acc[m][n][1] + 2.f*lor[n][1] + bs[1]; v1 = v1 > 0.f ? v1 : 0.f;
            float v2 = acc[m][n][2] + 2.f*lor[n][2] + bs[2]; v2 = v2 > 0.f ? v2 : 0.f;
            float v3 = acc[m][n][3] + 2.f*lor[n][3] + bs[3]; v3 = v3 > 0.f ? v3 : 0.f;
            us4 pk; pk.x = f2bf(v0); pk.y = f2bf(v1); pk.z = f2bf(v2); pk.w = f2bf(v3);
            *(us4*)(wsu + XBF_U + (size_t)brow*16384 + o0 + m*16 + hi*4) = pk;
        }
    }
}

// -------------------------------------- fused: 3 GAT layers + predictors ---
// (R15 structure; phase reorder: stage issues after bq reads drain, before
// A-reads, so the DMA departs earlier and A-read latency overlaps it)
__global__ __launch_bounds__(512, 4) void k_fused(
    const float* __restrict__ gbias,
    const float* __restrict__ nodeb, const float* __restrict__ adjb,
    const float* __restrict__ bondb,
    float* __restrict__ wsf, float* __restrict__ out)
{
    extern __shared__ ushort dyn[];
    ushort* Rr   = dyn;                         // x-mode swizzled (16384) / hT [4][64][68]
    ushort* bbuf = dyn + 17408;                 // 2 x [4 head][5 frag][512]
    float*  scr  = (float*)(dyn + 17408 + 20480);   // [768]
    ushort* wsu = (ushort*)wsf;
    int t = threadIdx.x;
    int w = t >> 6, ln = t & 63, lo = ln & 15, hi = ln >> 4;
    int head = w & 3, m0 = (w >> 2) * 32;       // PV/epilogue mapping
    int headH = w >> 1, c0h = w & 1;            // h-GEMM mapping
    int b = blockIdx.x;
    const ushort* xb = wsu + XBF_U + (size_t)b * 16384;

    // ---- stage x[b] -> Rr (x-mode, swizzled)
    #pragma unroll
    for (int i = 0; i < 4; ++i) {
        int flat = i*512 + t;
        int r = flat >> 5, ch = flat & 31;
        short8v v = *(const short8v*)(xb + (size_t)r*256 + ch*8);
        *(short8v*)&Rr[r*256 + ((ch ^ (r & 7)) << 3)] = v;
    }
    __syncthreads();

    float* es = scr;        // [4][64]
    float* ed = scr + 256;  // [4][64]

    // prologue: stage layer-0 slices 0,1 (barrier above drained vmcnt)
    {
        const ushort* wst0 = wsu + WST_U;
        stageW(bbuf +         headH*2560, wst0 +         headH*2560, c0h, ln);
        stageW(bbuf + 10240 + headH*2560, wst0 + 10240 + headH*2560, c0h, ln);
    }

    for (int l = 0; l < 3; ++l) {
        const ushort* wst  = wsu + WST_U + (size_t)l * 81920;
        const ushort* wstN = wsu + WST_U + (size_t)(l + 1) * 81920; // used only l<2
        const float*  hzp = wsf + HZ_OFF + (size_t)l*131072 + (size_t)b*256 + headH*64;

        float hzA = hzp[(c0h*2    )*16 + lo];
        float hzB = hzp[(c0h*2 + 1)*16 + lo];
        float ezs = wsf[EZ_OFF + (size_t)(l*2 + 0)*2048 + (size_t)b*4 + headH];
        float ezd = wsf[EZ_OFF + (size_t)(l*2 + 1)*2048 + (size_t)b*4 + headH];

        float4v acc[2][4], accE[4];
        float eInit = (lo == 0) ? ezs : (lo == 1 ? ezd : 0.f);
        #pragma unroll
        for (int m = 0; m < 4; ++m) {
            acc[0][m] = (float4v)(hzA);
            acc[1][m] = (float4v)(hzB);
            accE[m]   = (float4v)(eInit);
        }

        // ---- h-GEMM: 8 phases, counted vmcnt, no barriers
        #pragma unroll
        for (int kk = 0; kk < 8; ++kk) {
            if (kk == 7 && l == 2) {
                asm volatile("s_waitcnt vmcnt(0)" ::: "memory");
            } else if (c0h == 0) {
                asm volatile("s_waitcnt vmcnt(3)" ::: "memory");
            } else {
                asm volatile("s_waitcnt vmcnt(2)" ::: "memory");
            }
            const ushort* bb = bbuf + (kk&1)*10240 + headH*2560;
            short8v bq0 = *(const short8v*)(bb + (c0h*2    )*512 + ln*8);
            short8v bq1 = *(const short8v*)(bb + (c0h*2 + 1)*512 + ln*8);
            short8v bsd = {};
            if (c0h == 0) bsd = *(const short8v*)(bb + 2048 + ln*8);
            // stage next slice as soon as the bq reads have drained
            if (kk < 6) {
                asm volatile("s_waitcnt lgkmcnt(0)" ::: "memory");
                stageW(bbuf + (kk&1)*10240 + headH*2560,
                       wst + (size_t)(kk+2)*10240 + headH*2560, c0h, ln);
            } else if (l < 2) {
                asm volatile("s_waitcnt lgkmcnt(0)" ::: "memory");
                stageW(bbuf + (kk&1)*10240 + headH*2560,
                       wstN + (size_t)(kk-6)*10240 + headH*2560, c0h, ln);
            }
            short8v a0 = *(const short8v*)&Rr[xidx(     lo, kk*32 + hi*8)];
            short8v a1 = *(const short8v*)&Rr[xidx(16 + lo, kk*32 + hi*8)];
            short8v a2 = *(const short8v*)&Rr[xidx(32 + lo, kk*32 + hi*8)];
            short8v a3 = *(const short8v*)&Rr[xidx(48 + lo, kk*32 + hi*8)];
            __builtin_amdgcn_s_setprio(1);
            acc[0][0] = __builtin_amdgcn_mfma_f32_16x16x32_bf16(a0, bq0, acc[0][0], 0, 0, 0);
            acc[0][1] = __builtin_amdgcn_mfma_f32_16x16x32_bf16(a1, bq0, acc[0][1], 0, 0, 0);
            acc[0][2] = __builtin_amdgcn_mfma_f32_16x16x32_bf16(a2, bq0, acc[0][2], 0, 0, 0);
            acc[0][3] = __builtin_amdgcn_mfma_f32_16x16x32_bf16(a3, bq0, acc[0][3], 0, 0, 0);
            acc[1][0] = __builtin_amdgcn_mfma_f32_16x16x32_bf16(a0, bq1, acc[1][0], 0, 0, 0);
            acc[1][1] = __builtin_amdgcn_mfma_f32_16x16x32_bf16(a1, bq1, acc[1][1], 0, 0, 0);
            acc[1][2] = __builtin_amdgcn_mfma_f32_16x16x32_bf16(a2, bq1, acc[1][2], 0, 0, 0);
            acc[1][3] = __builtin_amdgcn_mfma_f32_16x16x32_bf16(a3, bq1, acc[1][3], 0, 0, 0);
            if (c0h == 0) {
                accE[0] = __builtin_amdgcn_mfma_f32_16x16x32_bf16(a0, bsd, accE[0], 0, 0, 0);
                accE[1] = __builtin_amdgcn_mfma_f32_16x16x32_bf16(a1, bsd, accE[1], 0, 0, 0);
                accE[2] = __builtin_amdgcn_mfma_f32_16x16x32_bf16(a2, bsd, accE[2], 0, 0, 0);
                accE[3] = __builtin_amdgcn_mfma_f32_16x16x32_bf16(a3, bsd, accE[3], 0, 0, 0);
            }
            __builtin_amdgcn_s_setprio(0);
        }

        // es/ed write (owner waves cover all 64 nodes of their head)
        if (c0h == 0) {
            if (lo == 0) {
                #pragma unroll
                for (int m = 0; m < 4; ++m)
                    *(float4*)&es[headH*64 + m*16 + hi*4] =
                        make_float4(accE[m][0], accE[m][1], accE[m][2], accE[m][3]);
            } else if (lo == 1) {
                #pragma unroll
                for (int m = 0; m < 4; ++m)
                    *(float4*)&ed[headH*64 + m*16 + hi*4] =
                        make_float4(accE[m][0], accE[m][1], accE[m][2], accE[m][3]);
            }
        }

        __syncthreads();    // sync_a: all x-mode reads done (drains vmcnt incl. prefetch)

        // ---- hT write (stride 68): hT[head][channel][node]
        #pragma unroll
        for (int cf = 0; cf < 2; ++cf)
            #pragma unroll
            for (int m = 0; m < 4; ++m) {
                uint2 pk;
                pk.x = cvtpk(acc[cf][m][0], acc[cf][m][1]);
                pk.y = cvtpk(acc[cf][m][2], acc[cf][m][3]);
                *(uint2*)&Rr[headH*4352 + ((c0h*2 + cf)*16 + lo)*68 + m*16 + hi*4] = pk;
            }

        __syncthreads();    // sync_b: hT + es/ed visible

        // ---- PV (swapped): out^T[c][r] = sum_j h[j][c]*p[r][j], p=exp(leaky(e))
        float4v acc2[4][2];
        #pragma unroll
        for (int m = 0; m < 4; ++m)
            #pragma unroll
            for (int n = 0; n < 2; ++n) acc2[m][n] = (float4v)(0.f);
        float psum[2] = {0.f, 0.f};
        #pragma unroll
        for (int kk = 0; kk < 2; ++kk) {
            short8v hb[4];
            #pragma unroll
            for (int m = 0; m < 4; ++m)
                hb[m] = *(const short8v*)&Rr[head*4352 + (m*16 + lo)*68 + kk*32 + hi*8];
            float4 e0 = *(const float4*)&es[head*64 + kk*32 + hi*8];
            float4 e1 = *(const float4*)&es[head*64 + kk*32 + hi*8 + 4];
            float ej[8] = {e0.x, e0.y, e0.z, e0.w, e1.x, e1.y, e1.z, e1.w};
            #pragma unroll
            for (int n = 0; n < 2; ++n) {
                float edr = ed[head*64 + m0 + n*16 + lo];
                float pvv[8]; float pp = 0.f;
                #pragma unroll
                for (int jj = 0; jj < 8; ++jj) {
                    float e = edr + ej[jj];
                    e = fmaxf(e, 0.2f * e);
                    float p = __expf(e);
                    pp += p;
                    pvv[jj] = p;
                }
                uint4v au;
                au.x = cvtpk(pvv[0], pvv[1]); au.y = cvtpk(pvv[2], pvv[3]);
                au.z = cvtpk(pvv[4], pvv[5]); au.w = cvtpk(pvv[6], pvv[7]);
                short8v af = __builtin_bit_cast(short8v, au);
                psum[n] += pp;
                __builtin_amdgcn_s_setprio(1);
                #pragma unroll
                for (int m = 0; m < 4; ++m)
                    acc2[m][n] = __builtin_amdgcn_mfma_f32_16x16x32_bf16(hb[m], af, acc2[m][n], 0, 0, 0);
                __builtin_amdgcn_s_setprio(0);
            }
        }
        float rs[2];
        #pragma unroll
        for (int n = 0; n < 2; ++n) {
            psum[n] += __shfl_xor(psum[n], 16);
            psum[n] += __shfl_xor(psum[n], 32);
            rs[n] = 1.0f / psum[n];
        }

        __syncthreads();    // sync_c: all hT reads done

        // ---- new-x write (x-mode, swizzled)
        #pragma unroll
        for (int m = 0; m < 4; ++m) {
            int c0 = head*64 + m*16 + hi*4;
            float b0f = gbias[l*256 + c0 + 0];
            float b1f = gbias[l*256 + c0 + 1];
            float b2f = gbias[l*256 + c0 + 2];
            float b3f = gbias[l*256 + c0 + 3];
            #pragma unroll
            for (int n = 0; n < 2; ++n) {
                int r = m0 + n*16 + lo;
                float v0 = acc2[m][n][0]*rs[n] + b0f; v0 = v0 > 0.f ? v0 : 0.f;
                float v1 = acc2[m][n][1]*rs[n] + b1f; v1 = v1 > 0.f ? v1 : 0.f;
                float v2 = acc2[m][n][2]*rs[n] + b2f; v2 = v2 > 0.f ? v2 : 0.f;
                float v3 = acc2[m][n][3]*rs[n] + b3f; v3 = v3 > 0.f ? v3 : 0.f;
                uint2 pk; pk.x = cvtpk(v0, v1); pk.y = cvtpk(v2, v3);
                *(uint2*)&Rr[xidx(r, c0)] = pk;
            }
        }

        __syncthreads();    // sync_d: new x ready
    }

    // --------------------------------------------------------- predictors --
    const ushort* pw = wsu + PW_U;
    int pq = w & 3, pn = w >> 2;
    if (pn == 0) {
        float4v p0 = (float4v)(0.f), p1 = (float4v)(0.f), p2 = (float4v)(0.f);
        P3 fA = loadP3(pw, lo, hi, 0);
        #pragma unroll
        for (int ii = 0; ii < 4; ++ii) {
            P3 fB = loadP3(pw, lo, hi, 2*ii + 1);
            {
                int kk = 2*ii;
                short8v a = *(const short8v*)&Rr[xidx(pq*16 + lo, kk*32 + hi*8)];
                p0 = __builtin_amdgcn_mfma_f32_16x16x32_bf16(a, fA.b0, p0, 0, 0, 0);
                p1 = __builtin_amdgcn_mfma_f32_16x16x32_bf16(a, fA.b1, p1, 0, 0, 0);
                p2 = __builtin_amdgcn_mfma_f32_16x16x32_bf16(a, fA.b2, p2, 0, 0, 0);
            }
            if (ii < 3) fA = loadP3(pw, lo, hi, 2*ii + 2);
            {
                int kk = 2*ii + 1;
                short8v a = *(const short8v*)&Rr[xidx(pq*16 + lo, kk*32 + hi*8)];
                p0 = __builtin_amdgcn_mfma_f32_16x16x32_bf16(a, fB.b0, p0, 0, 0, 0);
                p1 = __builtin_amdgcn_mfma_f32_16x16x32_bf16(a, fB.b1, p1, 0, 0, 0);
                p2 = __builtin_amdgcn_mfma_f32_16x16x32_bf16(a, fB.b2, p2, 0, 0, 0);
            }
        }
        __syncthreads();    // all x reads done; Rr reusable as f32 stage
        float* Rf = (float*)Rr;             // [64][68] f32
        #pragma unroll
        for (int qq = 0; qq < 4; ++qq) {
            int nd = pq*16 + hi*4 + qq;
            Rf[nd*68 + lo]      = p0[qq];
            Rf[nd*68 + 16 + lo] = p1[qq];
            Rf[nd*68 + 32 + lo] = p2[qq];
        }
    } else {
        float4v p3 = (float4v)(0.f), paux = (float4v)(0.f);
        P2 fA = loadP2(pw, lo, hi, 0);
        #pragma unroll
        for (int ii = 0; ii < 4; ++ii) {
            P2 fB = loadP2(pw, lo, hi, 2*ii + 1);
            {
                int kk = 2*ii;
                short8v a = *(const short8v*)&Rr[xidx(pq*16 + lo, kk*32 + hi*8)];
                p3   = __builtin_amdgcn_mfma_f32_16x16x32_bf16(a, fA.b3, p3, 0, 0, 0);
                paux = __builtin_amdgcn_mfma_f32_16x16x32_bf16(a, fA.b4, paux, 0, 0, 0);
            }
            if (ii < 3) fA = loadP2(pw, lo, hi, 2*ii + 2);
            {
                int kk = 2*ii + 1;
                short8v a = *(const short8v*)&Rr[xidx(pq*16 + lo, kk*32 + hi*8)];
                p3   = __builtin_amdgcn_mfma_f32_16x16x32_bf16(a, fB.b3, p3, 0, 0, 0);
                paux = __builtin_amdgcn_mfma_f32_16x16x32_bf16(a, fB.b4, paux, 0, 0, 0);
            }
        }
        __syncthreads();    // all x reads done
        float* Rf = (float*)Rr;
        #pragma unroll
        for (int qq = 0; qq < 4; ++qq) {
            int nd = pq*16 + hi*4 + qq;
            Rf[nd*68 + 48 + lo] = p3[qq];
            float v = paux[qq];
            if (lo == 0)      scr[nd] = v;                   // s1
            else if (lo == 1) scr[64 + nd] = v;              // s2
            else if (lo < 6)  scr[128 + nd*5 + (lo-2)] = v;  // t1
            else if (lo < 10) scr[448 + nd*5 + (lo-6)] = v;  // t2
        }
    }
    __syncthreads();

    // node recon: fully contiguous float4 sweep
    {
        const float* Rf = (const float*)Rr;
        #pragma unroll
        for (int it = 0; it < 2; ++it) {
            int idx = it*512 + t;
            int nd = idx >> 4, f0 = (idx & 15) * 4;
            float4 v = *(const float4*)&Rf[nd*68 + f0];
            float4 bv = *(const float4*)&nodeb[f0];
            v.x += bv.x; v.y += bv.y; v.z += bv.z; v.w += bv.w;
            *(float4*)&out[(size_t)b*4096 + (size_t)idx*4] = v;
        }
    }

    // adj logits: contiguous float4 sweep
    float ab = adjb[0];
    #pragma unroll
    for (int it = 0; it < 2; ++it) {
        int idx = it*512 + t;
        int flat = idx * 4;
        int i = flat >> 6, j0 = flat & 63;
        float4 v; float* vp = (float*)&v;
        #pragma unroll
        for (int uu = 0; uu < 4; ++uu) {
            int j = j0 + uu;
            float val;
            if (i == j)      val = 0.f;
            else if (i < j)  val = scr[i] + scr[64 + j] + ab;
            else             val = scr[j] + scr[64 + i] + ab;
            vp[uu] = val;
        }
        *(float4*)&out[2097152UL + (size_t)b*4096 + flat] = v;
    }

    // bond logits: contiguous float4 sweep
    float4 bb2 = *(const float4*)bondb;
    #pragma unroll
    for (int it = 0; it < 8; ++it) {
        int fl4 = it*512 + t;
        int i = fl4 >> 6, j = fl4 & 63;
        float4 v;
        if (i == j) { v.x = v.y = v.z = v.w = 0.f; }
        else {
            int a2 = i < j ? i : j, c2 = i < j ? j : i;
            v.x = scr[128 + a2*5 + 0] + scr[448 + c2*5 + 0] + bb2.x;
            v.y = scr[128 + a2*5 + 1] + scr[448 + c2*5 + 1] + bb2.y;
            v.z = scr[128 + a2*5 + 2] + scr[448 + c2*5 + 2] + bb2.z;
            v.w = scr[128 + a2*5 + 3] + scr[448 + c2*5 + 3] + bb2.w;
        }
        *(float4*)&out[4194304UL + (size_t)b*16384 + (size_t)fl4*4] = v;
    }
}

// ------------------------------------------------------------------ host ---
extern "C" void kernel_launch(void* const* d_in, const int* in_sizes, int n_in,
                              void* d_out, int out_size, void* d_ws, size_t ws_size,
                              hipStream_t stream)
{
    const float* z     = (const float*)d_in[0];
    const float* z2nw  = (const float*)d_in[1];
    const float* z2nb  = (const float*)d_in[2];
    const float* z2nA  = (const float*)d_in[3];
    const float* z2nB  = (const float*)d_in[4];
    const float* gatW  = (const float*)d_in[5];
    const float* asrc  = (const float*)d_in[6];
    const float* adst  = (const float*)d_in[7];
    const float* gbias = (const float*)d_in[8];
    const float* nodew = (const float*)d_in[9];
    const float* nodeb = (const float*)d_in[10];
    const float* nodeA = (const float*)d_in[11];
    const float* nodeB = (const float*)d_in[12];
    const float* adjw  = (const float*)d_in[13];
    const float* adjb  = (const float*)d_in[14];
    const float* adjA  = (const float*)d_in[15];
    const float* adjB  = (const float*)d_in[16];
    const float* bondw = (const float*)d_in[17];
    const float* bondb = (const float*)d_in[18];
    const float* bondA = (const float*)d_in[19];
    const float* bondB = (const float*)d_in[20];
    float* ws  = (float*)d_ws;
    float* out = (float*)d_out;

    k_setup<<<1592, 256, 0, stream>>>(z, z2nA, nodew, nodeA, nodeB,
                                      adjw, adjA, adjB, bondw, bondA, bondB,
                                      gatW, z2nw, asrc, adst, ws);
    k_z2n<<<536, 256, 0, stream>>>(z2nb, z2nB, asrc, adst, ws);
    k_fused<<<512, 512, 78848, stream>>>(gbias, nodeb, adjb, bondb, ws, out);
}

// Round 18
// 84.938 us; speedup vs baseline: 1.0112x; 1.0112x over previous
//
#include <hip/hip_runtime.h>

// B=512, N=64, H=256, LAT=128, HEADS=4, HC=64, NF=64, L=3, R=8, SCAL=2.0, NB=4, Din=384

typedef float float4v __attribute__((ext_vector_type(4)));
typedef short short8v __attribute__((ext_vector_type(8)));
typedef uint  uint4v  __attribute__((ext_vector_type(4)));

struct alignas(8) us4 { ushort x, y, z, w; };

// f32 ws offsets (floats)
#define ZA_OFF 0UL          // zA[512][8]
#define HZ_OFF 4096UL       // hz[3][512][256] f32
#define EZ_OFF 397312UL     // ez[3][2][512][4] f32
// ushort ws offsets (ushorts); f32 region ends at float 409600 -> ushort 819200
#define XBF_U   819200UL    // x bf16 [512][64][256]  (stored PRE-SWIZZLED per graph)
#define ZBF_U   9207808UL   // z bf16 [512][128]
#define GWBF_U  9273344UL   // gatW bf16 [3][256][384]
#define WZST_U  9568256UL   // z2n_w bf16 staging-ordered [64 bn][4 kk][4 wv][4 frag][64 ln][8]
#define PW_U    11665408UL  // pred weights bf16 [80][256]
#define WST_U   11759616UL  // wstage bf16 [3][8][4 head][5 frag][64 lane][8]

__device__ inline ushort f2bf(float f) {
    uint u = __float_as_uint(f);
    uint r = (u + 0x7FFFu + ((u >> 16) & 1u)) >> 16;
    return (ushort)r;
}
__device__ inline float bf2f(ushort u) { return __uint_as_float(((uint)u) << 16); }

__device__ inline uint cvtpk(float a, float b) {
    uint r;
    asm("v_cvt_pk_bf16_f32 %0, %1, %2" : "=v"(r) : "v"(a), "v"(b));
    return r;
}

// swizzled x layout index (ushort units): row r (0..63), ushort col cu (0..255)
__device__ inline int xidx(int r, int cu) {
    int ch = cu >> 3;
    return r * 256 + (((ch ^ (r & 7))) << 3) + (cu & 7);
}

struct P3 { short8v b0, b1, b2; };
__device__ inline P3 loadP3(const ushort* pw, int lo, int hi, int kk) {
    P3 f;
    f.b0 = *(const short8v*)(pw + (size_t)(      lo)*256 + kk*32 + hi*8);
    f.b1 = *(const short8v*)(pw + (size_t)(16  + lo)*256 + kk*32 + hi*8);
    f.b2 = *(const short8v*)(pw + (size_t)(32  + lo)*256 + kk*32 + hi*8);
    return f;
}
struct P2 { short8v b3, b4; };
__device__ inline P2 loadP2(const ushort* pw, int lo, int hi, int kk) {
    P2 f;
    f.b3 = *(const short8v*)(pw + (size_t)(48 + lo)*256 + kk*32 + hi*8);
    f.b4 = *(const short8v*)(pw + (size_t)(64 + lo)*256 + kk*32 + hi*8);
    return f;
}

__device__ inline void gll(const ushort* src, ushort* dst) {
    __builtin_amdgcn_global_load_lds(
        (const __attribute__((address_space(1))) void*)src,
        (__attribute__((address_space(3))) void*)dst, 16, 0, 0);
}

// wave-private slice staging: owner (c0h=0) frags {0,1,4}, other frags {2,3}
__device__ inline void stageW(ushort* dstHead, const ushort* srcHead, int c0h, int ln) {
    if (c0h == 0) {
        gll(srcHead +        ln*8, dstHead);
        gll(srcHead +  512 + ln*8, dstHead + 512);
        gll(srcHead + 2048 + ln*8, dstHead + 2048);
    } else {
        gll(srcHead + 1024 + ln*8, dstHead + 1024);
        gll(srcHead + 1536 + ln*8, dstHead + 1536);
    }
}

// z2n: wave stages its own 2048-us quarter of one slice (4 chunks of 512 us)
__device__ inline void stageZ(ushort* dst, const ushort* src, int ln) {
    #pragma unroll
    for (int c = 0; c < 4; ++c)
        gll(src + c*512 + ln*8, dst + c*512);
}

// ---------------------------------------------------------------- setup ----
__global__ __launch_bounds__(256) void k_setup(
    const float* __restrict__ z, const float* __restrict__ z2nA,
    const float* __restrict__ nodeW, const float* __restrict__ nodeA, const float* __restrict__ nodeB,
    const float* __restrict__ adjW, const float* __restrict__ adjA, const float* __restrict__ adjB,
    const float* __restrict__ bondW, const float* __restrict__ bondA, const float* __restrict__ bondB,
    const float* __restrict__ gatW, const float* __restrict__ z2nw,
    const float* __restrict__ asrcp, const float* __restrict__ adstp,
    float* __restrict__ wsf)
{
    ushort* wsu = (ushort*)wsf;
    int gid = blockIdx.x * 256 + threadIdx.x;
    if (gid < 4096) {                       // zA[b][r] = z[b]·A[r]
        int b = gid >> 3, r = gid & 7;
        const float* zp = z + (size_t)b * 128;
        const float* ap = z2nA + (size_t)r * 128;
        float s = 0.f;
        #pragma unroll 8
        for (int k = 0; k < 128; ++k) s += zp[k] * ap[k];
        wsf[ZA_OFF + gid] = s;
    } else if (gid < 24576) {               // pw[80][256] bf16, LoRA folded
        int idx = gid - 4096;
        int r = idx >> 8, c = idx & 255;
        float v = 0.f;
        if (r < 64) {
            float s = 0.f;
            #pragma unroll
            for (int k = 0; k < 8; ++k) s += nodeB[r*8+k] * nodeA[k*256+c];
            v = nodeW[r*256+c] + 2.0f * s;
        } else if (r < 66) {
            int off = (r - 64) * 256 + c;
            float s = 0.f;
            #pragma unroll
            for (int k = 0; k < 8; ++k) s += adjB[k] * adjA[k*512+off];
            v = adjW[off] + 2.0f * s;
        } else if (r < 70) {
            int q = r - 66;
            float s = 0.f;
            #pragma unroll
            for (int k = 0; k < 8; ++k) s += bondB[q*8+k] * bondA[k*512+c];
            v = bondW[q*512+c] + 2.0f * s;
        } else if (r < 74) {
            int q = r - 70;
            float s = 0.f;
            #pragma unroll
            for (int k = 0; k < 8; ++k) s += bondB[q*8+k] * bondA[k*512+256+c];
            v = bondW[q*512+256+c] + 2.0f * s;
        }
        wsu[PW_U + idx] = f2bf(v);
    } else if (gid < 55296) {               // wstage element (16B = 8 bf16)
        int idx = gid - 24576;               // [0, 30720)
        int lkk = idx / 1280;
        int rem = idx - lkk * 1280;
        int head = rem / 320;
        int rem2 = rem - head * 320;
        int frag = rem2 >> 6;
        int ln = rem2 & 63;
        int lo = ln & 15, hi = ln >> 4;
        int l = lkk >> 3, kk = lkk & 7;
        ushort* dst = wsu + WST_U + (size_t)idx * 8;
        if (frag < 4) {
            const float* srcw = gatW + ((size_t)(l*256 + head*64 + frag*16 + lo))*384 + kk*32 + hi*8;
            #pragma unroll
            for (int j = 0; j < 8; ++j) dst[j] = f2bf(srcw[j]);
        } else {
            float s[8] = {0.f,0.f,0.f,0.f,0.f,0.f,0.f,0.f};
            if (lo < 2) {
                const float* av = (lo == 0 ? asrcp : adstp) + l*256 + head*64;
                const float* wp = gatW + ((size_t)(l*256 + head*64))*384 + kk*32 + hi*8;
                for (int hc = 0; hc < 64; ++hc) {
                    float a = av[hc];
                    const float* wr = wp + (size_t)hc * 384;
                    #pragma unroll
                    for (int j = 0; j < 8; ++j) s[j] += wr[j] * a;
                }
            }
            #pragma unroll
            for (int j = 0; j < 8; ++j) dst[j] = f2bf(s[j]);
        }
    } else {                                // conversions
        int cid = gid - 55296;
        if (cid < 16384) {                  // z -> bf16
            float4 v = ((const float4*)z)[cid];
            us4 o; o.x = f2bf(v.x); o.y = f2bf(v.y); o.z = f2bf(v.z); o.w = f2bf(v.w);
            ((us4*)(wsu + ZBF_U))[cid] = o;
        } else if (cid < 90112) {           // gatW -> bf16
            int idx = cid - 16384;
            float4 v = ((const float4*)gatW)[idx];
            us4 o; o.x = f2bf(v.x); o.y = f2bf(v.y); o.z = f2bf(v.z); o.w = f2bf(v.w);
            ((us4*)(wsu + GWBF_U))[idx] = o;
        } else if (cid < 352256) {
            // z2n_w -> WZST, ONE 16B chunk per thread (coalesced writes)
            int c = cid - 90112;            // chunk index [0, 262144)
            int ln = c & 63, frag = (c >> 6) & 3, wv = (c >> 8) & 3,
                kk = (c >> 10) & 3, bn = c >> 12;
            int lo2 = ln & 15, hi2 = ln >> 4;
            const float* src = z2nw + (size_t)(bn*256 + wv*64 + frag*16 + lo2)*128
                                    + kk*32 + hi2*8;
            float4 v0 = *(const float4*)src;
            float4 v1 = *(const float4*)(src + 4);
            ushort* dst = wsu + WZST_U + (size_t)c * 8;
            us4 o0, o1;
            o0.x = f2bf(v0.x); o0.y = f2bf(v0.y); o0.z = f2bf(v0.z); o0.w = f2bf(v0.w);
            o1.x = f2bf(v1.x); o1.y = f2bf(v1.y); o1.z = f2bf(v1.z); o1.w = f2bf(v1.w);
            *(us4*)dst = o0;
            *(us4*)(dst + 4) = o1;
        }
    }
}

// ---------------------------------------- z_to_nodes + hz (merged grid) ----
__global__ __launch_bounds__(256) void k_z2n(
    const float* __restrict__ bias, const float* __restrict__ lB,
    const float* __restrict__ asrcp, const float* __restrict__ adstp,
    float* __restrict__ wsf)
{
    __shared__ ushort wbuf[16384];          // 2 x 8192 us (32 KB) W double-buffer
    ushort* wsu = (ushort*)wsf;
    int t = threadIdx.x;
    int w = t >> 6, ln = t & 63, lo = ln & 15, hi = ln >> 4;

    if (blockIdx.x >= 512) {
        // ---- hz part (24 blocks): hz[l][b][o2] = z[b]·Wz[l][o2]; ez dots
        int bid2 = blockIdx.x - 512;
        int l = bid2 >> 3, bg = bid2 & 7;
        const ushort* wz = wsu + GWBF_U + (size_t)l * 98304;   // [256][384]
        const ushort* zb = wsu + ZBF_U + (size_t)bg * 64 * 128;
        float4v acc[4][4];
        #pragma unroll
        for (int m = 0; m < 4; ++m)
            #pragma unroll
            for (int n = 0; n < 4; ++n) acc[m][n] = (float4v)(0.f);
        #pragma unroll
        for (int kk = 0; kk < 4; ++kk) {
            short8v a[4], bq[4];
            #pragma unroll
            for (int m = 0; m < 4; ++m)
                a[m] = *(const short8v*)(wz + (size_t)(w*64 + m*16 + lo)*384 + 256 + kk*32 + hi*8);
            #pragma unroll
            for (int n = 0; n < 4; ++n)
                bq[n] = *(const short8v*)(zb + (size_t)(n*16 + lo)*128 + kk*32 + hi*8);
            #pragma unroll
            for (int m = 0; m < 4; ++m)
                #pragma unroll
                for (int n = 0; n < 4; ++n)
                    acc[m][n] = __builtin_amdgcn_mfma_f32_16x16x32_bf16(a[m], bq[n], acc[m][n], 0, 0, 0);
        }
        float* hzp = wsf + HZ_OFF + (size_t)l * 131072;
        #pragma unroll
        for (int m = 0; m < 4; ++m)
            #pragma unroll
            for (int n = 0; n < 4; ++n)
                #pragma unroll
                for (int q = 0; q < 4; ++q)
                    hzp[(size_t)(bg*64 + n*16 + lo)*256 + w*64 + m*16 + hi*4 + q] = acc[m][n][q];
        float as_[4][4], ad_[4][4];
        #pragma unroll
        for (int m = 0; m < 4; ++m)
            #pragma unroll
            for (int q = 0; q < 4; ++q) {
                as_[m][q] = asrcp[l*256 + w*64 + m*16 + hi*4 + q];
                ad_[m][q] = adstp[l*256 + w*64 + m*16 + hi*4 + q];
            }
        #pragma unroll
        for (int n = 0; n < 4; ++n) {
            float ss = 0.f, dd = 0.f;
            #pragma unroll
            for (int m = 0; m < 4; ++m)
                #pragma unroll
                for (int q = 0; q < 4; ++q) {
                    ss += acc[m][n][q] * as_[m][q];
                    dd += acc[m][n][q] * ad_[m][q];
                }
            ss += __shfl_xor(ss, 16); ss += __shfl_xor(ss, 32);
            dd += __shfl_xor(dd, 16); dd += __shfl_xor(dd, 32);
            if (hi == 0) {
                int b = bg*64 + n*16 + lo;
                wsf[EZ_OFF + (size_t)(l*2 + 0)*2048 + (size_t)b*4 + w] = ss;
                wsf[EZ_OFF + (size_t)(l*2 + 1)*2048 + (size_t)b*4 + w] = dd;
            }
        }
        return;
    }

    // ---- z2n part (512 blocks): W via LDS-staged double buffer
    int bm = blockIdx.x >> 6, bn = blockIdx.x & 63;
    int brow0 = bm * 64;
    const ushort* wst = wsu + WZST_U + (size_t)bn * 32768;   // 4 slices x 8192 us
    const ushort* zb = wsu + ZBF_U;
    float4v acc[4][4];
    #pragma unroll
    for (int m = 0; m < 4; ++m)
        #pragma unroll
        for (int n = 0; n < 4; ++n) acc[m][n] = (float4v)(0.f);

    // prologue: stage slice 0 (each wave its own quarter)
    stageZ(wbuf + w*2048, wst + w*2048, ln);

    #pragma unroll
    for (int kk = 0; kk < 4; ++kk) {
        __syncthreads();   // slice kk landed (barrier drains vmcnt) + prev reads retired
        if (kk < 3)
            stageZ(wbuf + ((kk+1)&1)*8192 + w*2048,
                   wst + (size_t)(kk+1)*8192 + w*2048, ln);
        short8v a[4], bq[4];
        #pragma unroll
        for (int m = 0; m < 4; ++m)
            a[m] = *(const short8v*)&wbuf[(kk&1)*8192 + w*2048 + m*512 + ln*8];
        #pragma unroll
        for (int n = 0; n < 4; ++n)
            bq[n] = *(const short8v*)(zb + (size_t)(brow0 + n*16 + lo)*128 + kk*32 + hi*8);
        #pragma unroll
        for (int m = 0; m < 4; ++m)
            #pragma unroll
            for (int n = 0; n < 4; ++n)
                acc[m][n] = __builtin_amdgcn_mfma_f32_16x16x32_bf16(a[m], bq[n], acc[m][n], 0, 0, 0);
    }
    const float* zA = wsf + ZA_OFF;
    float4 za0[4], za1[4];
    #pragma unroll
    for (int n = 0; n < 4; ++n) {
        int brow = brow0 + n*16 + lo;
        za0[n] = *(const float4*)&zA[brow*8];
        za1[n] = *(const float4*)&zA[brow*8 + 4];
    }
    int o0 = bn * 256 + w * 64;
    #pragma unroll
    for (int m = 0; m < 4; ++m) {
        float lor[4][4]; float bs[4];
        #pragma unroll
        for (int q = 0; q < 4; ++q) {
            int o = o0 + m*16 + hi*4 + q;
            float4 b20 = *(const float4*)&lB[(size_t)o*8];
            float4 b21 = *(const float4*)&lB[(size_t)o*8 + 4];
            bs[q] = bias[o];
            #pragma unroll
            for (int n = 0; n < 4; ++n)
                lor[n][q] = za0[n].x*b20.x + za0[n].y*b20.y + za0[n].z*b20.z + za0[n].w*b20.w
                          + za1[n].x*b21.x + za1[n].y*b21.y + za1[n].z*b21.z + za1[n].w*b21.w;
        }
        // store pre-swizzled: x[graph][xidx(node=bn, col)]
        int col = w*64 + m*16 + hi*4;
        int sw = xidx(bn, col);
        #pragma unroll
        for (int n = 0; n < 4; ++n) {
            int brow = brow0 + n*16 + lo;
            float v0 = acc[m][n][0] + 2.f*lor[n][0] + bs[0]; v0 = v0 > 0.f ? v0 : 0.f;
            float v1 = acc[m][n][1] + 2.f*lor[n][1] + bs[1]; v1 = v1 > 0.f ? v1 : 0.f;
            float v2 = acc[m][n][2] + 2.f*lor[n][2] + bs[2]; v2 = v2 > 0.f ? v2 : 0.f;
            float v3 = acc[m][n][3] + 2.f*lor[n][3] + bs[3]; v3 = v3 > 0.f ? v3 : 0.f;
            us4 pk; pk.x = f2bf(v0); pk.y = f2bf(v1); pk.z = f2bf(v2); pk.w = f2bf(v3);
            *(us4*)(wsu + XBF_U + (size_t)brow*16384 + sw) = pk;
        }
    }
}

// -------------------------------------- fused: 3 GAT layers + predictors ---
// x arrives pre-swizzled -> staged by pure global_load_lds. Prologue weight
// stages issued before the x barrier (barrier drains vmcnt). Phase order =
// R16 (A-reads before stage issue).
__global__ __launch_bounds__(512, 4) void k_fused(
    const float* __restrict__ gbias,
    const float* __restrict__ nodeb, const float* __restrict__ adjb,
    const float* __restrict__ bondb,
    float* __restrict__ wsf, float* __restrict__ out)
{
    extern __shared__ ushort dyn[];
    ushort* Rr   = dyn;                         // x swizzled (16384) / hT [4][64][68]
    ushort* bbuf = dyn + 17408;                 // 2 x [4 head][5 frag][512]
    float*  scr  = (float*)(dyn + 17408 + 20480);   // [768]
    ushort* wsu = (ushort*)wsf;
    int t = threadIdx.x;
    int w = t >> 6, ln = t & 63, lo = ln & 15, hi = ln >> 4;
    int head = w & 3, m0 = (w >> 2) * 32;       // PV/epilogue mapping
    int headH = w >> 1, c0h = w & 1;            // h-GEMM mapping
    int b = blockIdx.x;
    const ushort* xb = wsu + XBF_U + (size_t)b * 16384;

    // ---- stage x[b] -> Rr via global_load_lds (already swizzled in global)
    #pragma unroll
    for (int i = 0; i < 4; ++i) {
        int base = i*4096 + w*512;              // us offset, wave-uniform
        gll(xb + base + ln*8, Rr + base);
    }
    // prologue: stage layer-0 slices 0,1 (drained by the barrier below)
    {
        const ushort* wst0 = wsu + WST_U;
        stageW(bbuf +         headH*2560, wst0 +         headH*2560, c0h, ln);
        stageW(bbuf + 10240 + headH*2560, wst0 + 10240 + headH*2560, c0h, ln);
    }
    __syncthreads();

    float* es = scr;        // [4][64]
    float* ed = scr + 256;  // [4][64]

    for (int l = 0; l < 3; ++l) {
        const ushort* wst  = wsu + WST_U + (size_t)l * 81920;
        const ushort* wstN = wsu + WST_U + (size_t)(l + 1) * 81920; // used only l<2
        const float*  hzp = wsf + HZ_OFF + (size_t)l*131072 + (size_t)b*256 + headH*64;

        float hzA = hzp[(c0h*2    )*16 + lo];
        float hzB = hzp[(c0h*2 + 1)*16 + lo];
        float ezs = wsf[EZ_OFF + (size_t)(l*2 + 0)*2048 + (size_t)b*4 + headH];
        float ezd = wsf[EZ_OFF + (size_t)(l*2 + 1)*2048 + (size_t)b*4 + headH];

        float4v acc[2][4], accE[4];
        float eInit = (lo == 0) ? ezs : (lo == 1 ? ezd : 0.f);
        #pragma unroll
        for (int m = 0; m < 4; ++m) {
            acc[0][m] = (float4v)(hzA);
            acc[1][m] = (float4v)(hzB);
            accE[m]   = (float4v)(eInit);
        }

        // ---- h-GEMM: 8 phases, counted vmcnt, no barriers
        #pragma unroll
        for (int kk = 0; kk < 8; ++kk) {
            if (kk == 7 && l == 2) {
                asm volatile("s_waitcnt vmcnt(0)" ::: "memory");
            } else if (c0h == 0) {
                asm volatile("s_waitcnt vmcnt(3)" ::: "memory");
            } else {
                asm volatile("s_waitcnt vmcnt(2)" ::: "memory");
            }
            const ushort* bb = bbuf + (kk&1)*10240 + headH*2560;
            short8v bq0 = *(const short8v*)(bb + (c0h*2    )*512 + ln*8);
            short8v bq1 = *(const short8v*)(bb + (c0h*2 + 1)*512 + ln*8);
            short8v bsd = {};
            if (c0h == 0) bsd = *(const short8v*)(bb + 2048 + ln*8);
            short8v a0 = *(const short8v*)&Rr[xidx(     lo, kk*32 + hi*8)];
            short8v a1 = *(const short8v*)&Rr[xidx(16 + lo, kk*32 + hi*8)];
            short8v a2 = *(const short8v*)&Rr[xidx(32 + lo, kk*32 + hi*8)];
            short8v a3 = *(const short8v*)&Rr[xidx(48 + lo, kk*32 + hi*8)];
            if (kk < 6) {
                asm volatile("s_waitcnt lgkmcnt(0)" ::: "memory");
                stageW(bbuf + (kk&1)*10240 + headH*2560,
                       wst + (size_t)(kk+2)*10240 + headH*2560, c0h, ln);
            } else if (l < 2) {
                asm volatile("s_waitcnt lgkmcnt(0)" ::: "memory");
                stageW(bbuf + (kk&1)*10240 + headH*2560,
                       wstN + (size_t)(kk-6)*10240 + headH*2560, c0h, ln);
            }
            __builtin_amdgcn_s_setprio(1);
            acc[0][0] = __builtin_amdgcn_mfma_f32_16x16x32_bf16(a0, bq0, acc[0][0], 0, 0, 0);
            acc[0][1] = __builtin_amdgcn_mfma_f32_16x16x32_bf16(a1, bq0, acc[0][1], 0, 0, 0);
            acc[0][2] = __builtin_amdgcn_mfma_f32_16x16x32_bf16(a2, bq0, acc[0][2], 0, 0, 0);
            acc[0][3] = __builtin_amdgcn_mfma_f32_16x16x32_bf16(a3, bq0, acc[0][3], 0, 0, 0);
            acc[1][0] = __builtin_amdgcn_mfma_f32_16x16x32_bf16(a0, bq1, acc[1][0], 0, 0, 0);
            acc[1][1] = __builtin_amdgcn_mfma_f32_16x16x32_bf16(a1, bq1, acc[1][1], 0, 0, 0);
            acc[1][2] = __builtin_amdgcn_mfma_f32_16x16x32_bf16(a2, bq1, acc[1][2], 0, 0, 0);
            acc[1][3] = __builtin_amdgcn_mfma_f32_16x16x32_bf16(a3, bq1, acc[1][3], 0, 0, 0);
            if (c0h == 0) {
                accE[0] = __builtin_amdgcn_mfma_f32_16x16x32_bf16(a0, bsd, accE[0], 0, 0, 0);
                accE[1] = __builtin_amdgcn_mfma_f32_16x16x32_bf16(a1, bsd, accE[1], 0, 0, 0);
                accE[2] = __builtin_amdgcn_mfma_f32_16x16x32_bf16(a2, bsd, accE[2], 0, 0, 0);
                accE[3] = __builtin_amdgcn_mfma_f32_16x16x32_bf16(a3, bsd, accE[3], 0, 0, 0);
            }
            __builtin_amdgcn_s_setprio(0);
        }

        // es/ed write (owner waves cover all 64 nodes of their head)
        if (c0h == 0) {
            if (lo == 0) {
                #pragma unroll
                for (int m = 0; m < 4; ++m)
                    *(float4*)&es[headH*64 + m*16 + hi*4] =
                        make_float4(accE[m][0], accE[m][1], accE[m][2], accE[m][3]);
            } else if (lo == 1) {
                #pragma unroll
                for (int m = 0; m < 4; ++m)
                    *(float4*)&ed[headH*64 + m*16 + hi*4] =
                        make_float4(accE[m][0], accE[m][1], accE[m][2], accE[m][3]);
            }
        }

        __syncthreads();    // sync_a: all x reads done (drains vmcnt incl. prefetch)

        // ---- hT write (stride 68): hT[head][channel][node]
        #pragma unroll
        for (int cf = 0; cf < 2; ++cf)
            #pragma unroll
            for (int m = 0; m < 4; ++m) {
                uint2 pk;
                pk.x = cvtpk(acc[cf][m][0], acc[cf][m][1]);
                pk.y = cvtpk(acc[cf][m][2], acc[cf][m][3]);
                *(uint2*)&Rr[headH*4352 + ((c0h*2 + cf)*16 + lo)*68 + m*16 + hi*4] = pk;
            }

        __syncthreads();    // sync_b: hT + es/ed visible

        // ---- PV (swapped): out^T[c][r] = sum_j h[j][c]*p[r][j], p=exp(leaky(e))
        float4v acc2[4][2];
        #pragma unroll
        for (int m = 0; m < 4; ++m)
            #pragma unroll
            for (int n = 0; n < 2; ++n) acc2[m][n] = (float4v)(0.f);
        float psum[2] = {0.f, 0.f};
        #pragma unroll
        for (int kk = 0; kk < 2; ++kk) {
            short8v hb[4];
            #pragma unroll
            for (int m = 0; m < 4; ++m)
                hb[m] = *(const short8v*)&Rr[head*4352 + (m*16 + lo)*68 + kk*32 + hi*8];
            float4 e0 = *(const float4*)&es[head*64 + kk*32 + hi*8];
            float4 e1 = *(const float4*)&es[head*64 + kk*32 + hi*8 + 4];
            float ej[8] = {e0.x, e0.y, e0.z, e0.w, e1.x, e1.y, e1.z, e1.w};
            #pragma unroll
            for (int n = 0; n < 2; ++n) {
                float edr = ed[head*64 + m0 + n*16 + lo];
                float pvv[8]; float pp = 0.f;
                #pragma unroll
                for (int jj = 0; jj < 8; ++jj) {
                    float e = edr + ej[jj];
                    e = fmaxf(e, 0.2f * e);
                    float p = __expf(e);
                    pp += p;
                    pvv[jj] = p;
                }
                uint4v au;
                au.x = cvtpk(pvv[0], pvv[1]); au.y = cvtpk(pvv[2], pvv[3]);
                au.z = cvtpk(pvv[4], pvv[5]); au.w = cvtpk(pvv[6], pvv[7]);
                short8v af = __builtin_bit_cast(short8v, au);
                psum[n] += pp;
                __builtin_amdgcn_s_setprio(1);
                #pragma unroll
                for (int m = 0; m < 4; ++m)
                    acc2[m][n] = __builtin_amdgcn_mfma_f32_16x16x32_bf16(hb[m], af, acc2[m][n], 0, 0, 0);
                __builtin_amdgcn_s_setprio(0);
            }
        }
        float rs[2];
        #pragma unroll
        for (int n = 0; n < 2; ++n) {
            psum[n] += __shfl_xor(psum[n], 16);
            psum[n] += __shfl_xor(psum[n], 32);
            rs[n] = 1.0f / psum[n];
        }

        __syncthreads();    // sync_c: all hT reads done

        // ---- new-x write (swizzled)
        #pragma unroll
        for (int m = 0; m < 4; ++m) {
            int c0 = head*64 + m*16 + hi*4;
            float b0f = gbias[l*256 + c0 + 0];
            float b1f = gbias[l*256 + c0 + 1];
            float b2f = gbias[l*256 + c0 + 2];
            float b3f = gbias[l*256 + c0 + 3];
            #pragma unroll
            for (int n = 0; n < 2; ++n) {
                int r = m0 + n*16 + lo;
                float v0 = acc2[m][n][0]*rs[n] + b0f; v0 = v0 > 0.f ? v0 : 0.f;
                float v1 = acc2[m][n][1]*rs[n] + b1f; v1 = v1 > 0.f ? v1 : 0.f;
                float v2 = acc2[m][n][2]*rs[n] + b2f; v2 = v2 > 0.f ? v2 : 0.f;
                float v3 = acc2[m][n][3]*rs[n] + b3f; v3 = v3 > 0.f ? v3 : 0.f;
                uint2 pk; pk.x = cvtpk(v0, v1); pk.y = cvtpk(v2, v3);
                *(uint2*)&Rr[xidx(r, c0)] = pk;
            }
        }

        __syncthreads();    // sync_d: new x ready
    }

    // --------------------------------------------------------- predictors --
    const ushort* pw = wsu + PW_U;
    int pq = w & 3, pn = w >> 2;
    if (pn == 0) {
        float4v p0 = (float4v)(0.f), p1 = (float4v)(0.f), p2 = (float4v)(0.f);
        P3 fA = loadP3(pw, lo, hi, 0);
        #pragma unroll
        for (int ii = 0; ii < 4; ++ii) {
            P3 fB = loadP3(pw, lo, hi, 2*ii + 1);
            {
                int kk = 2*ii;
                short8v a = *(const short8v*)&Rr[xidx(pq*16 + lo, kk*32 + hi*8)];
                p0 = __builtin_amdgcn_mfma_f32_16x16x32_bf16(a, fA.b0, p0, 0, 0, 0);
                p1 = __builtin_amdgcn_mfma_f32_16x16x32_bf16(a, fA.b1, p1, 0, 0, 0);
                p2 = __builtin_amdgcn_mfma_f32_16x16x32_bf16(a, fA.b2, p2, 0, 0, 0);
            }
            if (ii < 3) fA = loadP3(pw, lo, hi, 2*ii + 2);
            {
                int kk = 2*ii + 1;
                short8v a = *(const short8v*)&Rr[xidx(pq*16 + lo, kk*32 + hi*8)];
                p0 = __builtin_amdgcn_mfma_f32_16x16x32_bf16(a, fB.b0, p0, 0, 0, 0);
                p1 = __builtin_amdgcn_mfma_f32_16x16x32_bf16(a, fB.b1, p1, 0, 0, 0);
                p2 = __builtin_amdgcn_mfma_f32_16x16x32_bf16(a, fB.b2, p2, 0, 0, 0);
            }
        }
        __syncthreads();    // all x reads done; Rr reusable as f32 stage
        float* Rf = (float*)Rr;             // [64][68] f32
        #pragma unroll
        for (int qq = 0; qq < 4; ++qq) {
            int nd = pq*16 + hi*4 + qq;
            Rf[nd*68 + lo]      = p0[qq];
            Rf[nd*68 + 16 + lo] = p1[qq];
            Rf[nd*68 + 32 + lo] = p2[qq];
        }
    } else {
        float4v p3 = (float4v)(0.f), paux = (float4v)(0.f);
        P2 fA = loadP2(pw, lo, hi, 0);
        #pragma unroll
        for (int ii = 0; ii < 4; ++ii) {
            P2 fB = loadP2(pw, lo, hi, 2*ii + 1);
            {
                int kk = 2*ii;
                short8v a = *(const short8v*)&Rr[xidx(pq*16 + lo, kk*32 + hi*8)];
                p3   = __builtin_amdgcn_mfma_f32_16x16x32_bf16(a, fA.b3, p3, 0, 0, 0);
                paux = __builtin_amdgcn_mfma_f32_16x16x32_bf16(a, fA.b4, paux, 0, 0, 0);
            }
            if (ii < 3) fA = loadP2(pw, lo, hi, 2*ii + 2);
            {
                int kk = 2*ii + 1;
                short8v a = *(const short8v*)&Rr[xidx(pq*16 + lo, kk*32 + hi*8)];
                p3   = __builtin_amdgcn_mfma_f32_16x16x32_bf16(a, fB.b3, p3, 0, 0, 0);
                paux = __builtin_amdgcn_mfma_f32_16x16x32_bf16(a, fB.b4, paux, 0, 0, 0);
            }
        }
        __syncthreads();    // all x reads done
        float* Rf = (float*)Rr;
        #pragma unroll
        for (int qq = 0; qq < 4; ++qq) {
            int nd = pq*16 + hi*4 + qq;
            Rf[nd*68 + 48 + lo] = p3[qq];
            float v = paux[qq];
            if (lo == 0)      scr[nd] = v;                   // s1
            else if (lo == 1) scr[64 + nd] = v;              // s2
            else if (lo < 6)  scr[128 + nd*5 + (lo-2)] = v;  // t1
            else if (lo < 10) scr[448 + nd*5 + (lo-6)] = v;  // t2
        }
    }
    __syncthreads();

    // node recon: fully contiguous float4 sweep
    {
        const float* Rf = (const float*)Rr;
        #pragma unroll
        for (int it = 0; it < 2; ++it) {
            int idx = it*512 + t;
            int nd = idx >> 4, f0 = (idx & 15) * 4;
            float4 v = *(const float4*)&Rf[nd*68 + f0];
            float4 bv = *(const float4*)&nodeb[f0];
            v.x += bv.x; v.y += bv.y; v.z += bv.z; v.w += bv.w;
            *(float4*)&out[(size_t)b*4096 + (size_t)idx*4] = v;
        }
    }

    // adj logits: contiguous float4 sweep
    float ab = adjb[0];
    #pragma unroll
    for (int it = 0; it < 2; ++it) {
        int idx = it*512 + t;
        int flat = idx * 4;
        int i = flat >> 6, j0 = flat & 63;
        float4 v; float* vp = (float*)&v;
        #pragma unroll
        for (int uu = 0; uu < 4; ++uu) {
            int j = j0 + uu;
            float val;
            if (i == j)      val = 0.f;
            else if (i < j)  val = scr[i] + scr[64 + j] + ab;
            else             val = scr[j] + scr[64 + i] + ab;
            vp[uu] = val;
        }
        *(float4*)&out[2097152UL + (size_t)b*4096 + flat] = v;
    }

    // bond logits: contiguous float4 sweep
    float4 bb2 = *(const float4*)bondb;
    #pragma unroll
    for (int it = 0; it < 8; ++it) {
        int fl4 = it*512 + t;
        int i = fl4 >> 6, j = fl4 & 63;
        float4 v;
        if (i == j) { v.x = v.y = v.z = v.w = 0.f; }
        else {
            int a2 = i < j ? i : j, c2 = i < j ? j : i;
            v.x = scr[128 + a2*5 + 0] + scr[448 + c2*5 + 0] + bb2.x;
            v.y = scr[128 + a2*5 + 1] + scr[448 + c2*5 + 1] + bb2.y;
            v.z = scr[128 + a2*5 + 2] + scr[448 + c2*5 + 2] + bb2.z;
            v.w = scr[128 + a2*5 + 3] + scr[448 + c2*5 + 3] + bb2.w;
        }
        *(float4*)&out[4194304UL + (size_t)b*16384 + (size_t)fl4*4] = v;
    }
}

// ------------------------------------------------------------------ host ---
extern "C" void kernel_launch(void* const* d_in, const int* in_sizes, int n_in,
                              void* d_out, int out_size, void* d_ws, size_t ws_size,
                              hipStream_t stream)
{
    const float* z     = (const float*)d_in[0];
    const float* z2nw  = (const float*)d_in[1];
    const float* z2nb  = (const float*)d_in[2];
    const float* z2nA  = (const float*)d_in[3];
    const float* z2nB  = (const float*)d_in[4];
    const float* gatW  = (const float*)d_in[5];
    const float* asrc  = (const float*)d_in[6];
    const float* adst  = (const float*)d_in[7];
    const float* gbias = (const float*)d_in[8];
    const float* nodew = (const float*)d_in[9];
    const float* nodeb = (const float*)d_in[10];
    const float* nodeA = (const float*)d_in[11];
    const float* nodeB = (const float*)d_in[12];
    const float* adjw  = (const float*)d_in[13];
    const float* adjb  = (const float*)d_in[14];
    const float* adjA  = (const float*)d_in[15];
    const float* adjB  = (const float*)d_in[16];
    const float* bondw = (const float*)d_in[17];
    const float* bondb = (const float*)d_in[18];
    const float* bondA = (const float*)d_in[19];
    const float* bondB = (const float*)d_in[20];
    float* ws  = (float*)d_ws;
    float* out = (float*)d_out;

    k_setup<<<1592, 256, 0, stream>>>(z, z2nA, nodew, nodeA, nodeB,
                                      adjw, adjA, adjB, bondw, bondA, bondB,
                                      gatW, z2nw, asrc, adst, ws);
    k_z2n<<<536, 256, 0, stream>>>(z2nb, z2nB, asrc, adst, ws);
    k_fused<<<512, 512, 78848, stream>>>(gbias, nodeb, adjb, bondb, ws, out);
}

// Round 19
// 83.510 us; speedup vs baseline: 1.0285x; 1.0171x over previous
//
#include <hip/hip_runtime.h>

// B=512, N=64, H=256, LAT=128, HEADS=4, HC=64, NF=64, L=3, R=8, SCAL=2.0, NB=4, Din=384

typedef float float4v __attribute__((ext_vector_type(4)));
typedef short short8v __attribute__((ext_vector_type(8)));
typedef uint  uint4v  __attribute__((ext_vector_type(4)));

struct alignas(8) us4 { ushort x, y, z, w; };

// f32 ws offsets (floats)
#define ZA_OFF 0UL          // zA[512][8]
#define HZ_OFF 4096UL       // hz[3][512][256] f32
#define EZ_OFF 397312UL     // ez[3][2][512][4] f32
// ushort ws offsets (ushorts); f32 region ends at float 409600 -> ushort 819200
#define XBF_U   819200UL    // x bf16 [512][64][256]  (stored PRE-SWIZZLED per graph)
#define ZBF_U   9207808UL   // z bf16 [512][128]
#define GWBF_U  9273344UL   // gatW bf16 [3][256][384]
#define WZST_U  9568256UL   // z2n_w bf16 staging-ordered [64 bn][4 kk][4 wv][4 frag][64 ln][8]
#define PW_U    11665408UL  // pred weights bf16 [80][256]
#define WST_U   11759616UL  // wstage bf16 [3][8][4 head][5 frag][64 lane][8]

__device__ inline ushort f2bf(float f) {
    uint u = __float_as_uint(f);
    uint r = (u + 0x7FFFu + ((u >> 16) & 1u)) >> 16;
    return (ushort)r;
}
__device__ inline float bf2f(ushort u) { return __uint_as_float(((uint)u) << 16); }

__device__ inline uint cvtpk(float a, float b) {
    uint r;
    asm("v_cvt_pk_bf16_f32 %0, %1, %2" : "=v"(r) : "v"(a), "v"(b));
    return r;
}

// swizzled x layout index (ushort units): row r (0..63), ushort col cu (0..255)
__device__ inline int xidx(int r, int cu) {
    int ch = cu >> 3;
    return r * 256 + (((ch ^ (r & 7))) << 3) + (cu & 7);
}

struct P3 { short8v b0, b1, b2; };
__device__ inline P3 loadP3(const ushort* pw, int lo, int hi, int kk) {
    P3 f;
    f.b0 = *(const short8v*)(pw + (size_t)(      lo)*256 + kk*32 + hi*8);
    f.b1 = *(const short8v*)(pw + (size_t)(16  + lo)*256 + kk*32 + hi*8);
    f.b2 = *(const short8v*)(pw + (size_t)(32  + lo)*256 + kk*32 + hi*8);
    return f;
}
struct P2 { short8v b3, b4; };
__device__ inline P2 loadP2(const ushort* pw, int lo, int hi, int kk) {
    P2 f;
    f.b3 = *(const short8v*)(pw + (size_t)(48 + lo)*256 + kk*32 + hi*8);
    f.b4 = *(const short8v*)(pw + (size_t)(64 + lo)*256 + kk*32 + hi*8);
    return f;
}

__device__ inline void gll(const ushort* src, ushort* dst) {
    __builtin_amdgcn_global_load_lds(
        (const __attribute__((address_space(1))) void*)src,
        (__attribute__((address_space(3))) void*)dst, 16, 0, 0);
}

// wave-private slice staging: owner (c0h=0) frags {0,1,4}, other frags {2,3}
__device__ inline void stageW(ushort* dstHead, const ushort* srcHead, int c0h, int ln) {
    if (c0h == 0) {
        gll(srcHead +        ln*8, dstHead);
        gll(srcHead +  512 + ln*8, dstHead + 512);
        gll(srcHead + 2048 + ln*8, dstHead + 2048);
    } else {
        gll(srcHead + 1024 + ln*8, dstHead + 1024);
        gll(srcHead + 1536 + ln*8, dstHead + 1536);
    }
}

// z2n: wave stages its own 2048-us quarter of one slice (4 chunks of 512 us)
__device__ inline void stageZ(ushort* dst, const ushort* src, int ln) {
    #pragma unroll
    for (int c = 0; c < 4; ++c)
        gll(src + c*512 + ln*8, dst + c*512);
}

// ---------------------------------------------------------------- setup ----
// gid ranges:
//   [0,4096)         zA
//   [4096,24576)     pw (LoRA-folded predictor weights)
//   [24576,49152)    wstage frag<4 (24576 elements, 16B each)
//   [49152,58368)    vsd DENSE: one thread per (l,head,sd,c) -- all lanes hot,
//                    coalesced gatW reads. frag-4 rows lo>=2 left unwritten
//                    (provably unused: they feed accE cols 2..15, never read).
//   [58368,74752)    z -> bf16
//   [74752,148480)   gatW -> bf16
//   [148480,410624)  z2n_w -> WZST (coalesced 16B chunks)
__global__ __launch_bounds__(256) void k_setup(
    const float* __restrict__ z, const float* __restrict__ z2nA,
    const float* __restrict__ nodeW, const float* __restrict__ nodeA, const float* __restrict__ nodeB,
    const float* __restrict__ adjW, const float* __restrict__ adjA, const float* __restrict__ adjB,
    const float* __restrict__ bondW, const float* __restrict__ bondA, const float* __restrict__ bondB,
    const float* __restrict__ gatW, const float* __restrict__ z2nw,
    const float* __restrict__ asrcp, const float* __restrict__ adstp,
    float* __restrict__ wsf)
{
    ushort* wsu = (ushort*)wsf;
    int gid = blockIdx.x * 256 + threadIdx.x;
    if (gid < 4096) {                       // zA[b][r] = z[b]·A[r]
        int b = gid >> 3, r = gid & 7;
        const float* zp = z + (size_t)b * 128;
        const float* ap = z2nA + (size_t)r * 128;
        float s = 0.f;
        #pragma unroll 8
        for (int k = 0; k < 128; ++k) s += zp[k] * ap[k];
        wsf[ZA_OFF + gid] = s;
    } else if (gid < 24576) {               // pw[80][256] bf16, LoRA folded
        int idx = gid - 4096;
        int r = idx >> 8, c = idx & 255;
        float v = 0.f;
        if (r < 64) {
            float s = 0.f;
            #pragma unroll
            for (int k = 0; k < 8; ++k) s += nodeB[r*8+k] * nodeA[k*256+c];
            v = nodeW[r*256+c] + 2.0f * s;
        } else if (r < 66) {
            int off = (r - 64) * 256 + c;
            float s = 0.f;
            #pragma unroll
            for (int k = 0; k < 8; ++k) s += adjB[k] * adjA[k*512+off];
            v = adjW[off] + 2.0f * s;
        } else if (r < 70) {
            int q = r - 66;
            float s = 0.f;
            #pragma unroll
            for (int k = 0; k < 8; ++k) s += bondB[q*8+k] * bondA[k*512+c];
            v = bondW[q*512+c] + 2.0f * s;
        } else if (r < 74) {
            int q = r - 70;
            float s = 0.f;
            #pragma unroll
            for (int k = 0; k < 8; ++k) s += bondB[q*8+k] * bondA[k*512+256+c];
            v = bondW[q*512+256+c] + 2.0f * s;
        }
        wsu[PW_U + idx] = f2bf(v);
    } else if (gid < 49152) {               // wstage frag<4 (16B = 8 bf16)
        int idx = gid - 24576;               // [0, 24576)
        int lkk = idx >> 10;                 // (l*8+kk)
        int rem = idx & 1023;
        int head = rem >> 8;
        int rem2 = rem & 255;
        int frag = rem2 >> 6;
        int ln = rem2 & 63;
        int lo = ln & 15, hi = ln >> 4;
        int l = lkk >> 3, kk = lkk & 7;
        size_t lin = (((size_t)(lkk*4 + head))*5 + frag)*64 + ln;
        ushort* dst = wsu + WST_U + lin * 8;
        const float* srcw = gatW + ((size_t)(l*256 + head*64 + frag*16 + lo))*384 + kk*32 + hi*8;
        #pragma unroll
        for (int j = 0; j < 8; ++j) dst[j] = f2bf(srcw[j]);
    } else if (gid < 58368) {               // vsd dense: (l, head, sd, c)
        int idx = gid - 49152;               // [0, 9216)
        int c = idx % 384;
        int r3 = idx / 384;                  // (l*4+head)*2 + sd
        int sd = r3 & 1;
        int head = (r3 >> 1) & 3;
        int l = r3 >> 3;
        const float* av = (sd == 0 ? asrcp : adstp) + l*256 + head*64;
        const float* wp = gatW + ((size_t)(l*256 + head*64))*384 + c;
        float s = 0.f;
        #pragma unroll 8
        for (int hc = 0; hc < 64; ++hc) s += wp[(size_t)hc*384] * av[hc];
        int kk = c >> 5, within = c & 31;
        int hi = within >> 3, j = within & 7;
        int ln = hi*16 + sd;
        size_t lin = ((((size_t)(l*8 + kk)*4 + head))*5 + 4)*64 + ln;
        wsu[WST_U + lin*8 + j] = f2bf(s);
    } else {                                // conversions
        int cid = gid - 58368;
        if (cid < 16384) {                  // z -> bf16
            float4 v = ((const float4*)z)[cid];
            us4 o; o.x = f2bf(v.x); o.y = f2bf(v.y); o.z = f2bf(v.z); o.w = f2bf(v.w);
            ((us4*)(wsu + ZBF_U))[cid] = o;
        } else if (cid < 90112) {           // gatW -> bf16
            int idx = cid - 16384;
            float4 v = ((const float4*)gatW)[idx];
            us4 o; o.x = f2bf(v.x); o.y = f2bf(v.y); o.z = f2bf(v.z); o.w = f2bf(v.w);
            ((us4*)(wsu + GWBF_U))[idx] = o;
        } else if (cid < 352256) {
            // z2n_w -> WZST, ONE 16B chunk per thread (coalesced writes)
            int c = cid - 90112;            // chunk index [0, 262144)
            int ln = c & 63, frag = (c >> 6) & 3, wv = (c >> 8) & 3,
                kk = (c >> 10) & 3, bn = c >> 12;
            int lo2 = ln & 15, hi2 = ln >> 4;
            const float* src = z2nw + (size_t)(bn*256 + wv*64 + frag*16 + lo2)*128
                                    + kk*32 + hi2*8;
            float4 v0 = *(const float4*)src;
            float4 v1 = *(const float4*)(src + 4);
            ushort* dst = wsu + WZST_U + (size_t)c * 8;
            us4 o0, o1;
            o0.x = f2bf(v0.x); o0.y = f2bf(v0.y); o0.z = f2bf(v0.z); o0.w = f2bf(v0.w);
            o1.x = f2bf(v1.x); o1.y = f2bf(v1.y); o1.z = f2bf(v1.z); o1.w = f2bf(v1.w);
            *(us4*)dst = o0;
            *(us4*)(dst + 4) = o1;
        }
    }
}

// ---------------------------------------- z_to_nodes + hz (merged grid) ----
__global__ __launch_bounds__(256) void k_z2n(
    const float* __restrict__ bias, const float* __restrict__ lB,
    const float* __restrict__ asrcp, const float* __restrict__ adstp,
    float* __restrict__ wsf)
{
    __shared__ ushort wbuf[16384];          // 2 x 8192 us (32 KB) W double-buffer
    ushort* wsu = (ushort*)wsf;
    int t = threadIdx.x;
    int w = t >> 6, ln = t & 63, lo = ln & 15, hi = ln >> 4;

    if (blockIdx.x >= 512) {
        // ---- hz part (24 blocks): hz[l][b][o2] = z[b]·Wz[l][o2]; ez dots
        int bid2 = blockIdx.x - 512;
        int l = bid2 >> 3, bg = bid2 & 7;
        const ushort* wz = wsu + GWBF_U + (size_t)l * 98304;   // [256][384]
        const ushort* zb = wsu + ZBF_U + (size_t)bg * 64 * 128;
        float4v acc[4][4];
        #pragma unroll
        for (int m = 0; m < 4; ++m)
            #pragma unroll
            for (int n = 0; n < 4; ++n) acc[m][n] = (float4v)(0.f);
        #pragma unroll
        for (int kk = 0; kk < 4; ++kk) {
            short8v a[4], bq[4];
            #pragma unroll
            for (int m = 0; m < 4; ++m)
                a[m] = *(const short8v*)(wz + (size_t)(w*64 + m*16 + lo)*384 + 256 + kk*32 + hi*8);
            #pragma unroll
            for (int n = 0; n < 4; ++n)
                bq[n] = *(const short8v*)(zb + (size_t)(n*16 + lo)*128 + kk*32 + hi*8);
            #pragma unroll
            for (int m = 0; m < 4; ++m)
                #pragma unroll
                for (int n = 0; n < 4; ++n)
                    acc[m][n] = __builtin_amdgcn_mfma_f32_16x16x32_bf16(a[m], bq[n], acc[m][n], 0, 0, 0);
        }
        float* hzp = wsf + HZ_OFF + (size_t)l * 131072;
        #pragma unroll
        for (int m = 0; m < 4; ++m)
            #pragma unroll
            for (int n = 0; n < 4; ++n)
                #pragma unroll
                for (int q = 0; q < 4; ++q)
                    hzp[(size_t)(bg*64 + n*16 + lo)*256 + w*64 + m*16 + hi*4 + q] = acc[m][n][q];
        float as_[4][4], ad_[4][4];
        #pragma unroll
        for (int m = 0; m < 4; ++m)
            #pragma unroll
            for (int q = 0; q < 4; ++q) {
                as_[m][q] = asrcp[l*256 + w*64 + m*16 + hi*4 + q];
                ad_[m][q] = adstp[l*256 + w*64 + m*16 + hi*4 + q];
            }
        #pragma unroll
        for (int n = 0; n < 4; ++n) {
            float ss = 0.f, dd = 0.f;
            #pragma unroll
            for (int m = 0; m < 4; ++m)
                #pragma unroll
                for (int q = 0; q < 4; ++q) {
                    ss += acc[m][n][q] * as_[m][q];
                    dd += acc[m][n][q] * ad_[m][q];
                }
            ss += __shfl_xor(ss, 16); ss += __shfl_xor(ss, 32);
            dd += __shfl_xor(dd, 16); dd += __shfl_xor(dd, 32);
            if (hi == 0) {
                int b = bg*64 + n*16 + lo;
                wsf[EZ_OFF + (size_t)(l*2 + 0)*2048 + (size_t)b*4 + w] = ss;
                wsf[EZ_OFF + (size_t)(l*2 + 1)*2048 + (size_t)b*4 + w] = dd;
            }
        }
        return;
    }

    // ---- z2n part (512 blocks): W via LDS-staged double buffer
    int bm = blockIdx.x >> 6, bn = blockIdx.x & 63;
    int brow0 = bm * 64;
    const ushort* wst = wsu + WZST_U + (size_t)bn * 32768;   // 4 slices x 8192 us
    const ushort* zb = wsu + ZBF_U;
    float4v acc[4][4];
    #pragma unroll
    for (int m = 0; m < 4; ++m)
        #pragma unroll
        for (int n = 0; n < 4; ++n) acc[m][n] = (float4v)(0.f);

    // prologue: stage slice 0 (each wave its own quarter)
    stageZ(wbuf + w*2048, wst + w*2048, ln);

    #pragma unroll
    for (int kk = 0; kk < 4; ++kk) {
        __syncthreads();   // slice kk landed (barrier drains vmcnt) + prev reads retired
        if (kk < 3)
            stageZ(wbuf + ((kk+1)&1)*8192 + w*2048,
                   wst + (size_t)(kk+1)*8192 + w*2048, ln);
        short8v a[4], bq[4];
        #pragma unroll
        for (int m = 0; m < 4; ++m)
            a[m] = *(const short8v*)&wbuf[(kk&1)*8192 + w*2048 + m*512 + ln*8];
        #pragma unroll
        for (int n = 0; n < 4; ++n)
            bq[n] = *(const short8v*)(zb + (size_t)(brow0 + n*16 + lo)*128 + kk*32 + hi*8);
        #pragma unroll
        for (int m = 0; m < 4; ++m)
            #pragma unroll
            for (int n = 0; n < 4; ++n)
                acc[m][n] = __builtin_amdgcn_mfma_f32_16x16x32_bf16(a[m], bq[n], acc[m][n], 0, 0, 0);
    }
    const float* zA = wsf + ZA_OFF;
    float4 za0[4], za1[4];
    #pragma unroll
    for (int n = 0; n < 4; ++n) {
        int brow = brow0 + n*16 + lo;
        za0[n] = *(const float4*)&zA[brow*8];
        za1[n] = *(const float4*)&zA[brow*8 + 4];
    }
    int o0 = bn * 256 + w * 64;
    #pragma unroll
    for (int m = 0; m < 4; ++m) {
        float lor[4][4]; float bs[4];
        #pragma unroll
        for (int q = 0; q < 4; ++q) {
            int o = o0 + m*16 + hi*4 + q;
            float4 b20 = *(const float4*)&lB[(size_t)o*8];
            float4 b21 = *(const float4*)&lB[(size_t)o*8 + 4];
            bs[q] = bias[o];
            #pragma unroll
            for (int n = 0; n < 4; ++n)
                lor[n][q] = za0[n].x*b20.x + za0[n].y*b20.y + za0[n].z*b20.z + za0[n].w*b20.w
                          + za1[n].x*b21.x + za1[n].y*b21.y + za1[n].z*b21.z + za1[n].w*b21.w;
        }
        // store pre-swizzled: x[graph][xidx(node=bn, col)]
        int col = w*64 + m*16 + hi*4;
        int sw = xidx(bn, col);
        #pragma unroll
        for (int n = 0; n < 4; ++n) {
            int brow = brow0 + n*16 + lo;
            float v0 = acc[m][n][0] + 2.f*lor[n][0] + bs[0]; v0 = v0 > 0.f ? v0 : 0.f;
            float v1 = acc[m][n][1] + 2.f*lor[n][1] + bs[1]; v1 = v1 > 0.f ? v1 : 0.f;
            float v2 = acc[m][n][2] + 2.f*lor[n][2] + bs[2]; v2 = v2 > 0.f ? v2 : 0.f;
            float v3 = acc[m][n][3] + 2.f*lor[n][3] + bs[3]; v3 = v3 > 0.f ? v3 : 0.f;
            us4 pk; pk.x = f2bf(v0); pk.y = f2bf(v1); pk.z = f2bf(v2); pk.w = f2bf(v3);
            *(us4*)(wsu + XBF_U + (size_t)brow*16384 + sw) = pk;
        }
    }
}

// -------------------------------------- fused: 3 GAT layers + predictors ---
// (unchanged from R18 — best measured)
__global__ __launch_bounds__(512, 4) void k_fused(
    const float* __restrict__ gbias,
    const float* __restrict__ nodeb, const float* __restrict__ adjb,
    const float* __restrict__ bondb,
    float* __restrict__ wsf, float* __restrict__ out)
{
    extern __shared__ ushort dyn[];
    ushort* Rr   = dyn;                         // x swizzled (16384) / hT [4][64][68]
    ushort* bbuf = dyn + 17408;                 // 2 x [4 head][5 frag][512]
    float*  scr  = (float*)(dyn + 17408 + 20480);   // [768]
    ushort* wsu = (ushort*)wsf;
    int t = threadIdx.x;
    int w = t >> 6, ln = t & 63, lo = ln & 15, hi = ln >> 4;
    int head = w & 3, m0 = (w >> 2) * 32;       // PV/epilogue mapping
    int headH = w >> 1, c0h = w & 1;            // h-GEMM mapping
    int b = blockIdx.x;
    const ushort* xb = wsu + XBF_U + (size_t)b * 16384;

    // ---- stage x[b] -> Rr via global_load_lds (already swizzled in global)
    #pragma unroll
    for (int i = 0; i < 4; ++i) {
        int base = i*4096 + w*512;              // us offset, wave-uniform
        gll(xb + base + ln*8, Rr + base);
    }
    // prologue: stage layer-0 slices 0,1 (drained by the barrier below)
    {
        const ushort* wst0 = wsu + WST_U;
        stageW(bbuf +         headH*2560, wst0 +         headH*2560, c0h, ln);
        stageW(bbuf + 10240 + headH*2560, wst0 + 10240 + headH*2560, c0h, ln);
    }
    __syncthreads();

    float* es = scr;        // [4][64]
    float* ed = scr + 256;  // [4][64]

    for (int l = 0; l < 3; ++l) {
        const ushort* wst  = wsu + WST_U + (size_t)l * 81920;
        const ushort* wstN = wsu + WST_U + (size_t)(l + 1) * 81920; // used only l<2
        const float*  hzp = wsf + HZ_OFF + (size_t)l*131072 + (size_t)b*256 + headH*64;

        float hzA = hzp[(c0h*2    )*16 + lo];
        float hzB = hzp[(c0h*2 + 1)*16 + lo];
        float ezs = wsf[EZ_OFF + (size_t)(l*2 + 0)*2048 + (size_t)b*4 + headH];
        float ezd = wsf[EZ_OFF + (size_t)(l*2 + 1)*2048 + (size_t)b*4 + headH];

        float4v acc[2][4], accE[4];
        float eInit = (lo == 0) ? ezs : (lo == 1 ? ezd : 0.f);
        #pragma unroll
        for (int m = 0; m < 4; ++m) {
            acc[0][m] = (float4v)(hzA);
            acc[1][m] = (float4v)(hzB);
            accE[m]   = (float4v)(eInit);
        }

        // ---- h-GEMM: 8 phases, counted vmcnt, no barriers
        #pragma unroll
        for (int kk = 0; kk < 8; ++kk) {
            if (kk == 7 && l == 2) {
                asm volatile("s_waitcnt vmcnt(0)" ::: "memory");
            } else if (c0h == 0) {
                asm volatile("s_waitcnt vmcnt(3)" ::: "memory");
            } else {
                asm volatile("s_waitcnt vmcnt(2)" ::: "memory");
            }
            const ushort* bb = bbuf + (kk&1)*10240 + headH*2560;
            short8v bq0 = *(const short8v*)(bb + (c0h*2    )*512 + ln*8);
            short8v bq1 = *(const short8v*)(bb + (c0h*2 + 1)*512 + ln*8);
            short8v bsd = {};
            if (c0h == 0) bsd = *(const short8v*)(bb + 2048 + ln*8);
            short8v a0 = *(const short8v*)&Rr[xidx(     lo, kk*32 + hi*8)];
            short8v a1 = *(const short8v*)&Rr[xidx(16 + lo, kk*32 + hi*8)];
            short8v a2 = *(const short8v*)&Rr[xidx(32 + lo, kk*32 + hi*8)];
            short8v a3 = *(const short8v*)&Rr[xidx(48 + lo, kk*32 + hi*8)];
            if (kk < 6) {
                asm volatile("s_waitcnt lgkmcnt(0)" ::: "memory");
                stageW(bbuf + (kk&1)*10240 + headH*2560,
                       wst + (size_t)(kk+2)*10240 + headH*2560, c0h, ln);
            } else if (l < 2) {
                asm volatile("s_waitcnt lgkmcnt(0)" ::: "memory");
                stageW(bbuf + (kk&1)*10240 + headH*2560,
                       wstN + (size_t)(kk-6)*10240 + headH*2560, c0h, ln);
            }
            __builtin_amdgcn_s_setprio(1);
            acc[0][0] = __builtin_amdgcn_mfma_f32_16x16x32_bf16(a0, bq0, acc[0][0], 0, 0, 0);
            acc[0][1] = __builtin_amdgcn_mfma_f32_16x16x32_bf16(a1, bq0, acc[0][1], 0, 0, 0);
            acc[0][2] = __builtin_amdgcn_mfma_f32_16x16x32_bf16(a2, bq0, acc[0][2], 0, 0, 0);
            acc[0][3] = __builtin_amdgcn_mfma_f32_16x16x32_bf16(a3, bq0, acc[0][3], 0, 0, 0);
            acc[1][0] = __builtin_amdgcn_mfma_f32_16x16x32_bf16(a0, bq1, acc[1][0], 0, 0, 0);
            acc[1][1] = __builtin_amdgcn_mfma_f32_16x16x32_bf16(a1, bq1, acc[1][1], 0, 0, 0);
            acc[1][2] = __builtin_amdgcn_mfma_f32_16x16x32_bf16(a2, bq1, acc[1][2], 0, 0, 0);
            acc[1][3] = __builtin_amdgcn_mfma_f32_16x16x32_bf16(a3, bq1, acc[1][3], 0, 0, 0);
            if (c0h == 0) {
                accE[0] = __builtin_amdgcn_mfma_f32_16x16x32_bf16(a0, bsd, accE[0], 0, 0, 0);
                accE[1] = __builtin_amdgcn_mfma_f32_16x16x32_bf16(a1, bsd, accE[1], 0, 0, 0);
                accE[2] = __builtin_amdgcn_mfma_f32_16x16x32_bf16(a2, bsd, accE[2], 0, 0, 0);
                accE[3] = __builtin_amdgcn_mfma_f32_16x16x32_bf16(a3, bsd, accE[3], 0, 0, 0);
            }
            __builtin_amdgcn_s_setprio(0);
        }

        // es/ed write (owner waves cover all 64 nodes of their head)
        if (c0h == 0) {
            if (lo == 0) {
                #pragma unroll
                for (int m = 0; m < 4; ++m)
                    *(float4*)&es[headH*64 + m*16 + hi*4] =
                        make_float4(accE[m][0], accE[m][1], accE[m][2], accE[m][3]);
            } else if (lo == 1) {
                #pragma unroll
                for (int m = 0; m < 4; ++m)
                    *(float4*)&ed[headH*64 + m*16 + hi*4] =
                        make_float4(accE[m][0], accE[m][1], accE[m][2], accE[m][3]);
            }
        }

        __syncthreads();    // sync_a: all x reads done (drains vmcnt incl. prefetch)

        // ---- hT write (stride 68): hT[head][channel][node]
        #pragma unroll
        for (int cf = 0; cf < 2; ++cf)
            #pragma unroll
            for (int m = 0; m < 4; ++m) {
                uint2 pk;
                pk.x = cvtpk(acc[cf][m][0], acc[cf][m][1]);
                pk.y = cvtpk(acc[cf][m][2], acc[cf][m][3]);
                *(uint2*)&Rr[headH*4352 + ((c0h*2 + cf)*16 + lo)*68 + m*16 + hi*4] = pk;
            }

        __syncthreads();    // sync_b: hT + es/ed visible

        // ---- PV (swapped): out^T[c][r] = sum_j h[j][c]*p[r][j], p=exp(leaky(e))
        float4v acc2[4][2];
        #pragma unroll
        for (int m = 0; m < 4; ++m)
            #pragma unroll
            for (int n = 0; n < 2; ++n) acc2[m][n] = (float4v)(0.f);
        float psum[2] = {0.f, 0.f};
        #pragma unroll
        for (int kk = 0; kk < 2; ++kk) {
            short8v hb[4];
            #pragma unroll
            for (int m = 0; m < 4; ++m)
                hb[m] = *(const short8v*)&Rr[head*4352 + (m*16 + lo)*68 + kk*32 + hi*8];
            float4 e0 = *(const float4*)&es[head*64 + kk*32 + hi*8];
            float4 e1 = *(const float4*)&es[head*64 + kk*32 + hi*8 + 4];
            float ej[8] = {e0.x, e0.y, e0.z, e0.w, e1.x, e1.y, e1.z, e1.w};
            #pragma unroll
            for (int n = 0; n < 2; ++n) {
                float edr = ed[head*64 + m0 + n*16 + lo];
                float pvv[8]; float pp = 0.f;
                #pragma unroll
                for (int jj = 0; jj < 8; ++jj) {
                    float e = edr + ej[jj];
                    e = fmaxf(e, 0.2f * e);
                    float p = __expf(e);
                    pp += p;
                    pvv[jj] = p;
                }
                uint4v au;
                au.x = cvtpk(pvv[0], pvv[1]); au.y = cvtpk(pvv[2], pvv[3]);
                au.z = cvtpk(pvv[4], pvv[5]); au.w = cvtpk(pvv[6], pvv[7]);
                short8v af = __builtin_bit_cast(short8v, au);
                psum[n] += pp;
                __builtin_amdgcn_s_setprio(1);
                #pragma unroll
                for (int m = 0; m < 4; ++m)
                    acc2[m][n] = __builtin_amdgcn_mfma_f32_16x16x32_bf16(hb[m], af, acc2[m][n], 0, 0, 0);
                __builtin_amdgcn_s_setprio(0);
            }
        }
        float rs[2];
        #pragma unroll
        for (int n = 0; n < 2; ++n) {
            psum[n] += __shfl_xor(psum[n], 16);
            psum[n] += __shfl_xor(psum[n], 32);
            rs[n] = 1.0f / psum[n];
        }

        __syncthreads();    // sync_c: all hT reads done

        // ---- new-x write (swizzled)
        #pragma unroll
        for (int m = 0; m < 4; ++m) {
            int c0 = head*64 + m*16 + hi*4;
            float b0f = gbias[l*256 + c0 + 0];
            float b1f = gbias[l*256 + c0 + 1];
            float b2f = gbias[l*256 + c0 + 2];
            float b3f = gbias[l*256 + c0 + 3];
            #pragma unroll
            for (int n = 0; n < 2; ++n) {
                int r = m0 + n*16 + lo;
                float v0 = acc2[m][n][0]*rs[n] + b0f; v0 = v0 > 0.f ? v0 : 0.f;
                float v1 = acc2[m][n][1]*rs[n] + b1f; v1 = v1 > 0.f ? v1 : 0.f;
                float v2 = acc2[m][n][2]*rs[n] + b2f; v2 = v2 > 0.f ? v2 : 0.f;
                float v3 = acc2[m][n][3]*rs[n] + b3f; v3 = v3 > 0.f ? v3 : 0.f;
                uint2 pk; pk.x = cvtpk(v0, v1); pk.y = cvtpk(v2, v3);
                *(uint2*)&Rr[xidx(r, c0)] = pk;
            }
        }

        __syncthreads();    // sync_d: new x ready
    }

    // --------------------------------------------------------- predictors --
    const ushort* pw = wsu + PW_U;
    int pq = w & 3, pn = w >> 2;
    if (pn == 0) {
        float4v p0 = (float4v)(0.f), p1 = (float4v)(0.f), p2 = (float4v)(0.f);
        P3 fA = loadP3(pw, lo, hi, 0);
        #pragma unroll
        for (int ii = 0; ii < 4; ++ii) {
            P3 fB = loadP3(pw, lo, hi, 2*ii + 1);
            {
                int kk = 2*ii;
                short8v a = *(const short8v*)&Rr[xidx(pq*16 + lo, kk*32 + hi*8)];
                p0 = __builtin_amdgcn_mfma_f32_16x16x32_bf16(a, fA.b0, p0, 0, 0, 0);
                p1 = __builtin_amdgcn_mfma_f32_16x16x32_bf16(a, fA.b1, p1, 0, 0, 0);
                p2 = __builtin_amdgcn_mfma_f32_16x16x32_bf16(a, fA.b2, p2, 0, 0, 0);
            }
            if (ii < 3) fA = loadP3(pw, lo, hi, 2*ii + 2);
            {
                int kk = 2*ii + 1;
                short8v a = *(const short8v*)&Rr[xidx(pq*16 + lo, kk*32 + hi*8)];
                p0 = __builtin_amdgcn_mfma_f32_16x16x32_bf16(a, fB.b0, p0, 0, 0, 0);
                p1 = __builtin_amdgcn_mfma_f32_16x16x32_bf16(a, fB.b1, p1, 0, 0, 0);
                p2 = __builtin_amdgcn_mfma_f32_16x16x32_bf16(a, fB.b2, p2, 0, 0, 0);
            }
        }
        __syncthreads();    // all x reads done; Rr reusable as f32 stage
        float* Rf = (float*)Rr;             // [64][68] f32
        #pragma unroll
        for (int qq = 0; qq < 4; ++qq) {
            int nd = pq*16 + hi*4 + qq;
            Rf[nd*68 + lo]      = p0[qq];
            Rf[nd*68 + 16 + lo] = p1[qq];
            Rf[nd*68 + 32 + lo] = p2[qq];
        }
    } else {
        float4v p3 = (float4v)(0.f), paux = (float4v)(0.f);
        P2 fA = loadP2(pw, lo, hi, 0);
        #pragma unroll
        for (int ii = 0; ii < 4; ++ii) {
            P2 fB = loadP2(pw, lo, hi, 2*ii + 1);
            {
                int kk = 2*ii;
                short8v a = *(const short8v*)&Rr[xidx(pq*16 + lo, kk*32 + hi*8)];
                p3   = __builtin_amdgcn_mfma_f32_16x16x32_bf16(a, fA.b3, p3, 0, 0, 0);
                paux = __builtin_amdgcn_mfma_f32_16x16x32_bf16(a, fA.b4, paux, 0, 0, 0);
            }
            if (ii < 3) fA = loadP2(pw, lo, hi, 2*ii + 2);
            {
                int kk = 2*ii + 1;
                short8v a = *(const short8v*)&Rr[xidx(pq*16 + lo, kk*32 + hi*8)];
                p3   = __builtin_amdgcn_mfma_f32_16x16x32_bf16(a, fB.b3, p3, 0, 0, 0);
                paux = __builtin_amdgcn_mfma_f32_16x16x32_bf16(a, fB.b4, paux, 0, 0, 0);
            }
        }
        __syncthreads();    // all x reads done
        float* Rf = (float*)Rr;
        #pragma unroll
        for (int qq = 0; qq < 4; ++qq) {
            int nd = pq*16 + hi*4 + qq;
            Rf[nd*68 + 48 + lo] = p3[qq];
            float v = paux[qq];
            if (lo == 0)      scr[nd] = v;                   // s1
            else if (lo == 1) scr[64 + nd] = v;              // s2
            else if (lo < 6)  scr[128 + nd*5 + (lo-2)] = v;  // t1
            else if (lo < 10) scr[448 + nd*5 + (lo-6)] = v;  // t2
        }
    }
    __syncthreads();

    // node recon: fully contiguous float4 sweep
    {
        const float* Rf = (const float*)Rr;
        #pragma unroll
        for (int it = 0; it < 2; ++it) {
            int idx = it*512 + t;
            int nd = idx >> 4, f0 = (idx & 15) * 4;
            float4 v = *(const float4*)&Rf[nd*68 + f0];
            float4 bv = *(const float4*)&nodeb[f0];
            v.x += bv.x; v.y += bv.y; v.z += bv.z; v.w += bv.w;
            *(float4*)&out[(size_t)b*4096 + (size_t)idx*4] = v;
        }
    }

    // adj logits: contiguous float4 sweep
    float ab = adjb[0];
    #pragma unroll
    for (int it = 0; it < 2; ++it) {
        int idx = it*512 + t;
        int flat = idx * 4;
        int i = flat >> 6, j0 = flat & 63;
        float4 v; float* vp = (float*)&v;
        #pragma unroll
        for (int uu = 0; uu < 4; ++uu) {
            int j = j0 + uu;
            float val;
            if (i == j)      val = 0.f;
            else if (i < j)  val = scr[i] + scr[64 + j] + ab;
            else             val = scr[j] + scr[64 + i] + ab;
            vp[uu] = val;
        }
        *(float4*)&out[2097152UL + (size_t)b*4096 + flat] = v;
    }

    // bond logits: contiguous float4 sweep
    float4 bb2 = *(const float4*)bondb;
    #pragma unroll
    for (int it = 0; it < 8; ++it) {
        int fl4 = it*512 + t;
        int i = fl4 >> 6, j = fl4 & 63;
        float4 v;
        if (i == j) { v.x = v.y = v.z = v.w = 0.f; }
        else {
            int a2 = i < j ? i : j, c2 = i < j ? j : i;
            v.x = scr[128 + a2*5 + 0] + scr[448 + c2*5 + 0] + bb2.x;
            v.y = scr[128 + a2*5 + 1] + scr[448 + c2*5 + 1] + bb2.y;
            v.z = scr[128 + a2*5 + 2] + scr[448 + c2*5 + 2] + bb2.z;
            v.w = scr[128 + a2*5 + 3] + scr[448 + c2*5 + 3] + bb2.w;
        }
        *(float4*)&out[4194304UL + (size_t)b*16384 + (size_t)fl4*4] = v;
    }
}

// ------------------------------------------------------------------ host ---
extern "C" void kernel_launch(void* const* d_in, const int* in_sizes, int n_in,
                              void* d_out, int out_size, void* d_ws, size_t ws_size,
                              hipStream_t stream)
{
    const float* z     = (const float*)d_in[0];
    const float* z2nw  = (const float*)d_in[1];
    const float* z2nb  = (const float*)d_in[2];
    const float* z2nA  = (const float*)d_in[3];
    const float* z2nB  = (const float*)d_in[4];
    const float* gatW  = (const float*)d_in[5];
    const float* asrc  = (const float*)d_in[6];
    const float* adst  = (const float*)d_in[7];
    const float* gbias = (const float*)d_in[8];
    const float* nodew = (const float*)d_in[9];
    const float* nodeb = (const float*)d_in[10];
    const float* nodeA = (const float*)d_in[11];
    const float* nodeB = (const float*)d_in[12];
    const float* adjw  = (const float*)d_in[13];
    const float* adjb  = (const float*)d_in[14];
    const float* adjA  = (const float*)d_in[15];
    const float* adjB  = (const float*)d_in[16];
    const float* bondw = (const float*)d_in[17];
    const float* bondb = (const float*)d_in[18];
    const float* bondA = (const float*)d_in[19];
    const float* bondB = (const float*)d_in[20];
    float* ws  = (float*)d_ws;
    float* out = (float*)d_out;

    k_setup<<<1604, 256, 0, stream>>>(z, z2nA, nodew, nodeA, nodeB,
                                      adjw, adjA, adjB, bondw, bondA, bondB,
                                      gatW, z2nw, asrc, adst, ws);
    k_z2n<<<536, 256, 0, stream>>>(z2nb, z2nB, asrc, adst, ws);
    k_fused<<<512, 512, 78848, stream>>>(gbias, nodeb, adjb, bondb, ws, out);
}